// Round 3
// baseline (584.081 us; speedup 1.0000x reference)
//
#include <hip/hip_runtime.h>

// MHA fused pipeline for MI355X (gfx950), f16 MFMA + fp32 accumulate.
// Round 3: FIX attn sV staging under-coverage (cols 64..127 of the V^T tile
// were never written -> uninitialized-LDS NaN into the PV MFMA). This bug
// existed in rounds 1-2 and confounded the global_load_lds bisection.
//
// ws layout (bytes):
//   xh     @ 0          : 4096x2048 f16  (x cast)      [dead after gemm<0>]
//   Vth    @ 0          : [64][64][2048] f16 (V^T)     [overlays xh]
//   wqkvt  @ 16777216   : 6144x2048 f16  (Wqkv^T)     [dead after gemm<0>]
//   Oh     @ 16777216   : 4096x2048 f16  (attn out)    [overlays wqkvt]
//   Qh     @ 41943040   : [64 bh][2048][64] f16
//   Kh     @ 58720256   : [64 bh][2048][64] f16
//   Vh     @ 75497472   : [64 bh][2048][64] f16        [dead after vtrans]
//   woutt  @ 92274688   : 2048x2048 f16  (Wout^T)
//   total 100663296 B = 96 MB

typedef _Float16 half8 __attribute__((ext_vector_type(8)));
typedef float floatx4 __attribute__((ext_vector_type(4)));

__device__ __forceinline__ floatx4 mfma16(half8 a, half8 b, floatx4 c) {
  return __builtin_amdgcn_mfma_f32_16x16x32_f16(a, b, c, 0, 0, 0);
}

// ---------------------------------------------------------------- cvt_x
__global__ __launch_bounds__(256) void cvt_x_kernel(const float* __restrict__ x,
                                                    _Float16* __restrict__ xh) {
  int idx = blockIdx.x * 256 + threadIdx.x;  // 8 elems each, 8.4M total
  const floatx4* p = (const floatx4*)x + (size_t)idx * 2;
  floatx4 a = p[0], b = p[1];
  half8 o;
#pragma unroll
  for (int j = 0; j < 4; ++j) { o[j] = (_Float16)a[j]; o[4 + j] = (_Float16)b[j]; }
  *((half8*)xh + idx) = o;
}

// ------------------------------------------------------- cvt + transpose W
// W (Kd x Nd) f32 row-major  ->  Wt (Nd x Kd) f16 row-major
__global__ __launch_bounds__(256) void cvt_wt_kernel(const float* __restrict__ W,
                                                     _Float16* __restrict__ Wt,
                                                     int Kd, int Nd) {
  __shared__ float tile[64][65];
  int n0 = blockIdx.x * 64, k0 = blockIdx.y * 64;
  int tid = threadIdx.x;
#pragma unroll
  for (int it = 0; it < 4; ++it) {
    int r = (tid >> 4) + it * 16;   // k-local
    int c = (tid & 15) * 4;         // n-local
    floatx4 v = *(const floatx4*)(W + (size_t)(k0 + r) * Nd + n0 + c);
    tile[r][c + 0] = v[0]; tile[r][c + 1] = v[1];
    tile[r][c + 2] = v[2]; tile[r][c + 3] = v[3];
  }
  __syncthreads();
#pragma unroll
  for (int it = 0; it < 2; ++it) {
    int r = (tid >> 3) + it * 32;   // n-local
    int c = (tid & 7) * 8;          // k-local
    half8 o;
#pragma unroll
    for (int j = 0; j < 8; ++j) o[j] = (_Float16)tile[c + j][r];
    *(half8*)(Wt + (size_t)(n0 + r) * Kd + k0 + c) = o;
  }
}

// ---------------------------------------------------------------- GEMM
// C(128x128 tile) = A(MxK) @ Bt(NxK)^T + bias.
// MODE 0: epilogue scatters f16 into Q/K/V [bh][s][64] per-head layout.
// MODE 1: epilogue writes fp32 Co[m*Nd + n].
// Staging: explicit half8 global load -> XOR-swizzled ds_write_b128 so
// fragment ds_read_b128 is bank-conflict-free per 16-lane phase.
// LDS layout: sX[row*64 + (chunk ^ (row&7))*8] holds global k8-chunk `chunk`.
template <int MODE>
__global__ __launch_bounds__(256) void gemm_f16_kernel(
    const _Float16* __restrict__ A, const _Float16* __restrict__ Bt,
    const float* __restrict__ bias, int Kd, int Nd,
    _Float16* __restrict__ Qd, _Float16* __restrict__ Kkd,
    _Float16* __restrict__ Vd, float* __restrict__ Co) {
  __shared__ __align__(16) _Float16 sA[128 * 64];
  __shared__ __align__(16) _Float16 sB[128 * 64];
  int tid = threadIdx.x, w = tid >> 6, l = tid & 63;
  int lr = l & 15, lq = l >> 4;
  int m0 = blockIdx.y * 128, n0 = blockIdx.x * 128;
  int wrow = (w >> 1) * 64, wcol = (w & 1) * 64;

  floatx4 z4 = {0.f, 0.f, 0.f, 0.f};
  floatx4 acc[4][4];
#pragma unroll
  for (int i = 0; i < 4; ++i)
#pragma unroll
    for (int j = 0; j < 4; ++j) acc[i][j] = z4;

  // staging: wave w covers tile rows [w*32, w*32+32): 4 t-chunks x 8 rows,
  // lane l -> row offset srow = l>>3, k8-chunk c = l&7 (coalesced 16B loads)
  int srow = l >> 3;
  int c = l & 7;
  const _Float16* aG = A + (size_t)(m0 + w * 32 + srow) * Kd + c * 8;
  const _Float16* bG = Bt + (size_t)(n0 + w * 32 + srow) * Kd + c * 8;
  int swz = (c ^ srow) * 8;  // (row&7)==srow for all t

  for (int kt = 0; kt < Kd; kt += 64) {
    half8 av[4], bv[4];
#pragma unroll
    for (int t = 0; t < 4; ++t) {
      av[t] = *(const half8*)(aG + (size_t)t * 8 * Kd + kt);
      bv[t] = *(const half8*)(bG + (size_t)t * 8 * Kd + kt);
    }
    __syncthreads();  // previous iteration's ds_reads complete
#pragma unroll
    for (int t = 0; t < 4; ++t) {
      int row = w * 32 + t * 8 + srow;
      *(half8*)&sA[row * 64 + swz] = av[t];
      *(half8*)&sB[row * 64 + swz] = bv[t];
    }
    __syncthreads();
#pragma unroll
    for (int ks = 0; ks < 2; ++ks) {
      half8 af[4], bf[4];
#pragma unroll
      for (int i = 0; i < 4; ++i) {
        int ar = wrow + i * 16 + lr;
        int br = wcol + i * 16 + lr;
        int sl = (((ks << 2) | lq) ^ (lr & 7)) * 8;  // row&7 == lr&7
        af[i] = *(const half8*)&sA[ar * 64 + sl];
        bf[i] = *(const half8*)&sB[br * 64 + sl];
      }
#pragma unroll
      for (int i = 0; i < 4; ++i)
#pragma unroll
        for (int j = 0; j < 4; ++j) acc[i][j] = mfma16(af[i], bf[j], acc[i][j]);
    }
  }

  // epilogue: C/D layout col = lane&15, row = (lane>>4)*4 + reg (m89/m91)
  if (MODE == 0) {
    int which = n0 >> 11;  // 0:q 1:k 2:v, uniform per block
    _Float16* dst = (which == 0) ? Qd : (which == 1) ? Kkd : Vd;
#pragma unroll
    for (int j = 0; j < 4; ++j) {
      int n = n0 + wcol + j * 16 + lr;
      float bj = bias[n];
      int hh = (n & 2047) >> 6, dd = n & 63;
#pragma unroll
      for (int i = 0; i < 4; ++i)
#pragma unroll
        for (int r = 0; r < 4; ++r) {
          int m = m0 + wrow + i * 16 + lq * 4 + r;
          int bb = m >> 11, t = m & 2047;
          dst[((size_t)(bb * 32 + hh) * 2048 + (size_t)t) * 64 + dd] =
              (_Float16)(acc[i][j][r] + bj);
        }
    }
  } else {
#pragma unroll
    for (int j = 0; j < 4; ++j) {
      int n = n0 + wcol + j * 16 + lr;
      float bj = bias[n];
#pragma unroll
      for (int i = 0; i < 4; ++i)
#pragma unroll
        for (int r = 0; r < 4; ++r) {
          int m = m0 + wrow + i * 16 + lq * 4 + r;
          Co[(size_t)m * Nd + n] = acc[i][j][r] + bj;
        }
    }
  }
}

// ---------------------------------------------------------------- RoPE
// In-place on Q and K, rotary_dim=32 (pairs d and d+16), base 10000.
__global__ __launch_bounds__(256) void rope_kernel(_Float16* __restrict__ Qp,
                                                   _Float16* __restrict__ Kp) {
  int idx = blockIdx.x * 256 + threadIdx.x;  // (qk, bh, t)
  int t = idx & 2047;
  int bh = (idx >> 11) & 63;
  _Float16* base = ((idx >> 17) ? Kp : Qp) + ((size_t)bh * 2048 + t) * 64;
  half8* hp = (half8*)base;
  half8 h0 = hp[0], h1 = hp[1], h2 = hp[2], h3 = hp[3];  // elems 0..31
  float v[32];
#pragma unroll
  for (int j = 0; j < 8; ++j) {
    v[j] = (float)h0[j];      v[8 + j] = (float)h1[j];
    v[16 + j] = (float)h2[j]; v[24 + j] = (float)h3[j];
  }
  float o[32];
#pragma unroll
  for (int j = 0; j < 16; ++j) {
    // 10000^(-j/16) = exp(-j * ln(10000)/16)
    float freq = __expf(-(float)j * 0.57564627324851148f);
    float ang = (float)t * freq;
    float cs = cosf(ang), sn = sinf(ang);
    o[j] = v[j] * cs - v[j + 16] * sn;
    o[j + 16] = v[j] * sn + v[j + 16] * cs;
  }
  half8 g0, g1, g2, g3;
#pragma unroll
  for (int j = 0; j < 8; ++j) {
    g0[j] = (_Float16)o[j];      g1[j] = (_Float16)o[8 + j];
    g2[j] = (_Float16)o[16 + j]; g3[j] = (_Float16)o[24 + j];
  }
  hp[0] = g0; hp[1] = g1; hp[2] = g2; hp[3] = g3;  // elems 32..63 untouched
}

// ---------------------------------------------------------------- V^T
// V [bh][2048][64] -> Vt [bh][64][2048], 64x64 tiles.
__global__ __launch_bounds__(256) void vtrans_kernel(const _Float16* __restrict__ V,
                                                     _Float16* __restrict__ Vt) {
  __shared__ __align__(16) _Float16 tile[64][72];
  int s0 = blockIdx.x * 64;
  int bh = blockIdx.y;
  const _Float16* Vb = V + (size_t)bh * 2048 * 64;
  _Float16* Vtb = Vt + (size_t)bh * 64 * 2048;
  int tid = threadIdx.x;
#pragma unroll
  for (int it = 0; it < 2; ++it) {
    int r = (tid >> 3) + it * 32;   // s-local
    int cc = (tid & 7) * 8;         // d
    *(half8*)&tile[r][cc] = *(const half8*)(Vb + (size_t)(s0 + r) * 64 + cc);
  }
  __syncthreads();
#pragma unroll
  for (int it = 0; it < 2; ++it) {
    int r = (tid >> 3) + it * 32;   // d-local
    int cc = (tid & 7) * 8;         // s-local
    half8 o;
#pragma unroll
    for (int j = 0; j < 8; ++j) o[j] = tile[cc + j][r];
    *(half8*)(Vtb + (size_t)r * 2048 + s0 + cc) = o;
  }
}

// ---------------------------------------------------------------- attention
// Flash-style causal attention. Block = (bh, 128-row q-tile), 4 waves,
// each wave owns 32 q rows. Q frags in registers; K/Vt staged in padded
// LDS; P round-trips per-wave-private LDS rows (m120 pattern).
__global__ __launch_bounds__(256) void attn_kernel(
    const _Float16* __restrict__ Q, const _Float16* __restrict__ Kk,
    const _Float16* __restrict__ Vt, _Float16* __restrict__ O) {
  constexpr int S = 2048;
  int qt = 15 - (int)blockIdx.x;  // heavy (long) q-tiles dispatch first
  int bh = blockIdx.y;
  int bb = bh >> 5, hh = bh & 31;
  const _Float16* Qb = Q + (size_t)bh * S * 64;
  const _Float16* Kb = Kk + (size_t)bh * S * 64;
  const _Float16* Vb = Vt + (size_t)bh * 64 * S;

  __shared__ __align__(16) _Float16 sK[128 * 72];
  __shared__ __align__(16) _Float16 sV[64 * 136];
  __shared__ __align__(16) _Float16 sP[128 * 136];

  int tid = threadIdx.x, w = tid >> 6, l = tid & 63;
  int lr = l & 15, lq = l >> 4;
  int q0 = qt * 128;

  // Q fragments (A-operand: row = lane&15, k = (lane>>4)*8 + j), scale folded
  half8 qf[2][2];
#pragma unroll
  for (int rt = 0; rt < 2; ++rt)
#pragma unroll
    for (int ks = 0; ks < 2; ++ks) {
      half8 v = *(const half8*)(Qb + (size_t)(q0 + w * 32 + rt * 16 + lr) * 64 +
                                ks * 32 + lq * 8);
      qf[rt][ks] = v * (_Float16)0.125f;  // 1/sqrt(64), exact in f16
    }

  floatx4 z4 = {0.f, 0.f, 0.f, 0.f};
  floatx4 Oa[2][4];
  float m_i[2][4], l_i[2][4];
#pragma unroll
  for (int rt = 0; rt < 2; ++rt)
#pragma unroll
    for (int r = 0; r < 4; ++r) { m_i[rt][r] = -1e30f; l_i[rt][r] = 0.f; }
#pragma unroll
  for (int rt = 0; rt < 2; ++rt)
#pragma unroll
    for (int vt = 0; vt < 4; ++vt) Oa[rt][vt] = z4;

  for (int jt = 0; jt <= qt; ++jt) {
    int kv0 = jt * 128;
    // stage K tile (128 x 64) and Vt tile (64 x 128) -- FULL coverage
    {
      int rk = tid >> 3, ck = (tid & 7) * 8;
#pragma unroll
      for (int it = 0; it < 4; ++it)
        *(half8*)&sK[(rk + it * 32) * 72 + ck] =
            *(const half8*)(Kb + (size_t)(kv0 + rk + it * 32) * 64 + ck);
      int rv = tid >> 4, cv = (tid & 15) * 8;  // 16 rows x 128 cols per pass
#pragma unroll
      for (int it = 0; it < 4; ++it)
        *(half8*)&sV[(rv + it * 16) * 136 + cv] =
            *(const half8*)(Vb + (size_t)(rv + it * 16) * S + kv0 + cv);
    }
    __syncthreads();

    // S = (Q*scale) @ K^T : 2 rowtiles x 8 coltiles per wave
    floatx4 Sa[2][8];
#pragma unroll
    for (int rt = 0; rt < 2; ++rt)
#pragma unroll
      for (int ct = 0; ct < 8; ++ct) Sa[rt][ct] = z4;
#pragma unroll
    for (int ks = 0; ks < 2; ++ks) {
      half8 kf[8];
#pragma unroll
      for (int ct = 0; ct < 8; ++ct)
        kf[ct] = *(const half8*)&sK[(ct * 16 + lr) * 72 + ks * 32 + lq * 8];
#pragma unroll
      for (int ct = 0; ct < 8; ++ct) {
        Sa[0][ct] = mfma16(qf[0][ks], kf[ct], Sa[0][ct]);
        Sa[1][ct] = mfma16(qf[1][ks], kf[ct], Sa[1][ct]);
      }
    }

    if (jt == qt) {  // causal mask on diagonal tile (same tile origin)
#pragma unroll
      for (int rt = 0; rt < 2; ++rt) {
        int row = w * 32 + rt * 16 + lq * 4;
#pragma unroll
        for (int ct = 0; ct < 8; ++ct) {
          int col = ct * 16 + lr;
#pragma unroll
          for (int r = 0; r < 4; ++r)
            if (col > row + r) Sa[rt][ct][r] = -1e30f;
        }
      }
    }

    // online softmax per q-row (row shared by 16 lanes of same quad)
#pragma unroll
    for (int rt = 0; rt < 2; ++rt) {
#pragma unroll
      for (int r = 0; r < 4; ++r) {
        float mx = Sa[rt][0][r];
#pragma unroll
        for (int ct = 1; ct < 8; ++ct) mx = fmaxf(mx, Sa[rt][ct][r]);
        mx = fmaxf(mx, __shfl_xor(mx, 1));
        mx = fmaxf(mx, __shfl_xor(mx, 2));
        mx = fmaxf(mx, __shfl_xor(mx, 4));
        mx = fmaxf(mx, __shfl_xor(mx, 8));
        float mprev = m_i[rt][r];
        float mnew = fmaxf(mprev, mx);
        float alpha = __expf(mprev - mnew);
        m_i[rt][r] = mnew;
        int prow = (w * 32 + rt * 16 + lq * 4 + r) * 136;
        float rs = 0.f;
#pragma unroll
        for (int ct = 0; ct < 8; ++ct) {
          float p = __expf(Sa[rt][ct][r] - mnew);
          rs += p;
          sP[prow + ct * 16 + lr] = (_Float16)p;
        }
        rs += __shfl_xor(rs, 1);
        rs += __shfl_xor(rs, 2);
        rs += __shfl_xor(rs, 4);
        rs += __shfl_xor(rs, 8);
        l_i[rt][r] = l_i[rt][r] * alpha + rs;
#pragma unroll
        for (int vt = 0; vt < 4; ++vt) Oa[rt][vt][r] *= alpha;
      }
    }

    // O += P @ V  (P rows are wave-private in sP; same-wave LDS is in-order)
#pragma unroll
    for (int ks = 0; ks < 4; ++ks) {
      half8 vf[4], pf[2];
#pragma unroll
      for (int vt = 0; vt < 4; ++vt)
        vf[vt] = *(const half8*)&sV[(vt * 16 + lr) * 136 + ks * 32 + lq * 8];
#pragma unroll
      for (int rt = 0; rt < 2; ++rt)
        pf[rt] = *(const half8*)&sP[(w * 32 + rt * 16 + lr) * 136 + ks * 32 + lq * 8];
#pragma unroll
      for (int rt = 0; rt < 2; ++rt)
#pragma unroll
        for (int vt = 0; vt < 4; ++vt) Oa[rt][vt] = mfma16(pf[rt], vf[vt], Oa[rt][vt]);
    }
    __syncthreads();
  }

  // epilogue: O[b, t, h*64+d] f16
#pragma unroll
  for (int rt = 0; rt < 2; ++rt)
#pragma unroll
    for (int r = 0; r < 4; ++r) {
      float inv = 1.0f / l_i[rt][r];
      int trow = q0 + w * 32 + rt * 16 + lq * 4 + r;
      size_t rowoff = ((size_t)(bb * 2048 + trow)) * 2048 + hh * 64;
#pragma unroll
      for (int vt = 0; vt < 4; ++vt)
        O[rowoff + vt * 16 + lr] = (_Float16)(Oa[rt][vt][r] * inv);
    }
}

// ---------------------------------------------------------------- launch
extern "C" void kernel_launch(void* const* d_in, const int* in_sizes, int n_in,
                              void* d_out, int out_size, void* d_ws, size_t ws_size,
                              hipStream_t stream) {
  (void)in_sizes; (void)n_in; (void)out_size; (void)ws_size;
  const float* x = (const float*)d_in[0];
  const float* Wqkv = (const float*)d_in[1];
  const float* bqkv = (const float*)d_in[2];
  const float* Wout = (const float*)d_in[3];
  const float* bout = (const float*)d_in[4];
  float* out = (float*)d_out;
  char* ws = (char*)d_ws;

  _Float16* xh    = (_Float16*)(ws + 0);
  _Float16* Vth   = (_Float16*)(ws + 0);          // overlays xh (dead)
  _Float16* wqkvt = (_Float16*)(ws + 16777216);
  _Float16* Oh    = (_Float16*)(ws + 16777216);   // overlays wqkvt (dead)
  _Float16* Qh    = (_Float16*)(ws + 41943040);
  _Float16* Kh    = (_Float16*)(ws + 58720256);
  _Float16* Vh    = (_Float16*)(ws + 75497472);
  _Float16* woutt = (_Float16*)(ws + 92274688);   // total 96 MB

  cvt_x_kernel<<<4096, 256, 0, stream>>>(x, xh);
  cvt_wt_kernel<<<dim3(96, 32), 256, 0, stream>>>(Wqkv, wqkvt, 2048, 6144);
  cvt_wt_kernel<<<dim3(32, 32), 256, 0, stream>>>(Wout, woutt, 2048, 2048);
  gemm_f16_kernel<0><<<dim3(48, 32), 256, 0, stream>>>(
      xh, wqkvt, bqkv, 2048, 6144, Qh, Kh, Vh, nullptr);
  rope_kernel<<<1024, 256, 0, stream>>>(Qh, Kh);
  vtrans_kernel<<<dim3(32, 64), 256, 0, stream>>>(Vh, Vth);
  attn_kernel<<<dim3(16, 64), 256, 0, stream>>>(Qh, Kh, Vth, Oh);
  gemm_f16_kernel<1><<<dim3(16, 32), 256, 0, stream>>>(
      Oh, woutt, bout, 2048, 2048, nullptr, nullptr, nullptr, out);
}

// Round 4
// 496.327 us; speedup vs baseline: 1.1768x; 1.1768x over previous
//
#include <hip/hip_runtime.h>

// MHA fused pipeline for MI355X (gfx950), f16 MFMA + fp32 accumulate.
// Round 4: attention restructured to compute S^T (swap MFMA operands).
//  - softmax row-reduce: 2 shuffles (xor 16/32) instead of 8 per-row chains
//  - P^T stays in registers as the B-operand of v_mfma_f32_16x16x16_f16
//    (C-layout row=quad*4+r == B-layout k=quad*4+j)  -> sP LDS deleted
//  - LDS 70656 -> 35840 B (2 -> 4 blocks/CU by LDS)
//  - exp2-domain softmax, log2e*scale folded into Q fragments
//  - epilogue transposes O^T via reused sK for coalesced half8 stores
//
// ws layout (bytes):
//   xh     @ 0          : 4096x2048 f16  (x cast)      [dead after gemm<0>]
//   Vth    @ 0          : [64][64][2048] f16 (V^T)     [overlays xh]
//   wqkvt  @ 16777216   : 6144x2048 f16  (Wqkv^T)     [dead after gemm<0>]
//   Oh     @ 16777216   : 4096x2048 f16  (attn out)    [overlays wqkvt]
//   Qh     @ 41943040   : [64 bh][2048][64] f16
//   Kh     @ 58720256   : [64 bh][2048][64] f16
//   Vh     @ 75497472   : [64 bh][2048][64] f16        [dead after vtrans]
//   woutt  @ 92274688   : 2048x2048 f16  (Wout^T)
//   total 100663296 B = 96 MB

typedef _Float16 half8 __attribute__((ext_vector_type(8)));
typedef _Float16 half4 __attribute__((ext_vector_type(4)));
typedef float floatx4 __attribute__((ext_vector_type(4)));

__device__ __forceinline__ floatx4 mfma16(half8 a, half8 b, floatx4 c) {
  return __builtin_amdgcn_mfma_f32_16x16x32_f16(a, b, c, 0, 0, 0);
}
__device__ __forceinline__ floatx4 mfma16k16(half4 a, half4 b, floatx4 c) {
  return __builtin_amdgcn_mfma_f32_16x16x16f16(a, b, c, 0, 0, 0);
}

// ---------------------------------------------------------------- cvt_x
__global__ __launch_bounds__(256) void cvt_x_kernel(const float* __restrict__ x,
                                                    _Float16* __restrict__ xh) {
  int idx = blockIdx.x * 256 + threadIdx.x;  // 8 elems each, 8.4M total
  const floatx4* p = (const floatx4*)x + (size_t)idx * 2;
  floatx4 a = p[0], b = p[1];
  half8 o;
#pragma unroll
  for (int j = 0; j < 4; ++j) { o[j] = (_Float16)a[j]; o[4 + j] = (_Float16)b[j]; }
  *((half8*)xh + idx) = o;
}

// ------------------------------------------------------- cvt + transpose W
// W (Kd x Nd) f32 row-major  ->  Wt (Nd x Kd) f16 row-major
__global__ __launch_bounds__(256) void cvt_wt_kernel(const float* __restrict__ W,
                                                     _Float16* __restrict__ Wt,
                                                     int Kd, int Nd) {
  __shared__ float tile[64][65];
  int n0 = blockIdx.x * 64, k0 = blockIdx.y * 64;
  int tid = threadIdx.x;
#pragma unroll
  for (int it = 0; it < 4; ++it) {
    int r = (tid >> 4) + it * 16;   // k-local
    int c = (tid & 15) * 4;         // n-local
    floatx4 v = *(const floatx4*)(W + (size_t)(k0 + r) * Nd + n0 + c);
    tile[r][c + 0] = v[0]; tile[r][c + 1] = v[1];
    tile[r][c + 2] = v[2]; tile[r][c + 3] = v[3];
  }
  __syncthreads();
#pragma unroll
  for (int it = 0; it < 2; ++it) {
    int r = (tid >> 3) + it * 32;   // n-local
    int c = (tid & 7) * 8;          // k-local
    half8 o;
#pragma unroll
    for (int j = 0; j < 8; ++j) o[j] = (_Float16)tile[c + j][r];
    *(half8*)(Wt + (size_t)(n0 + r) * Kd + k0 + c) = o;
  }
}

// ---------------------------------------------------------------- GEMM
// C(128x128 tile) = A(MxK) @ Bt(NxK)^T + bias.  (unchanged from round 3)
template <int MODE>
__global__ __launch_bounds__(256) void gemm_f16_kernel(
    const _Float16* __restrict__ A, const _Float16* __restrict__ Bt,
    const float* __restrict__ bias, int Kd, int Nd,
    _Float16* __restrict__ Qd, _Float16* __restrict__ Kkd,
    _Float16* __restrict__ Vd, float* __restrict__ Co) {
  __shared__ __align__(16) _Float16 sA[128 * 64];
  __shared__ __align__(16) _Float16 sB[128 * 64];
  int tid = threadIdx.x, w = tid >> 6, l = tid & 63;
  int lr = l & 15, lq = l >> 4;
  int m0 = blockIdx.y * 128, n0 = blockIdx.x * 128;
  int wrow = (w >> 1) * 64, wcol = (w & 1) * 64;

  floatx4 z4 = {0.f, 0.f, 0.f, 0.f};
  floatx4 acc[4][4];
#pragma unroll
  for (int i = 0; i < 4; ++i)
#pragma unroll
    for (int j = 0; j < 4; ++j) acc[i][j] = z4;

  int srow = l >> 3;
  int c = l & 7;
  const _Float16* aG = A + (size_t)(m0 + w * 32 + srow) * Kd + c * 8;
  const _Float16* bG = Bt + (size_t)(n0 + w * 32 + srow) * Kd + c * 8;
  int swz = (c ^ srow) * 8;  // (row&7)==srow for all t

  for (int kt = 0; kt < Kd; kt += 64) {
    half8 av[4], bv[4];
#pragma unroll
    for (int t = 0; t < 4; ++t) {
      av[t] = *(const half8*)(aG + (size_t)t * 8 * Kd + kt);
      bv[t] = *(const half8*)(bG + (size_t)t * 8 * Kd + kt);
    }
    __syncthreads();  // previous iteration's ds_reads complete
#pragma unroll
    for (int t = 0; t < 4; ++t) {
      int row = w * 32 + t * 8 + srow;
      *(half8*)&sA[row * 64 + swz] = av[t];
      *(half8*)&sB[row * 64 + swz] = bv[t];
    }
    __syncthreads();
#pragma unroll
    for (int ks = 0; ks < 2; ++ks) {
      half8 af[4], bf[4];
#pragma unroll
      for (int i = 0; i < 4; ++i) {
        int ar = wrow + i * 16 + lr;
        int br = wcol + i * 16 + lr;
        int sl = (((ks << 2) | lq) ^ (lr & 7)) * 8;  // row&7 == lr&7
        af[i] = *(const half8*)&sA[ar * 64 + sl];
        bf[i] = *(const half8*)&sB[br * 64 + sl];
      }
#pragma unroll
      for (int i = 0; i < 4; ++i)
#pragma unroll
        for (int j = 0; j < 4; ++j) acc[i][j] = mfma16(af[i], bf[j], acc[i][j]);
    }
  }

  // epilogue: C/D layout col = lane&15, row = (lane>>4)*4 + reg (m89/m91)
  if (MODE == 0) {
    int which = n0 >> 11;  // 0:q 1:k 2:v, uniform per block
    _Float16* dst = (which == 0) ? Qd : (which == 1) ? Kkd : Vd;
#pragma unroll
    for (int j = 0; j < 4; ++j) {
      int n = n0 + wcol + j * 16 + lr;
      float bj = bias[n];
      int hh = (n & 2047) >> 6, dd = n & 63;
#pragma unroll
      for (int i = 0; i < 4; ++i)
#pragma unroll
        for (int r = 0; r < 4; ++r) {
          int m = m0 + wrow + i * 16 + lq * 4 + r;
          int bb = m >> 11, t = m & 2047;
          dst[((size_t)(bb * 32 + hh) * 2048 + (size_t)t) * 64 + dd] =
              (_Float16)(acc[i][j][r] + bj);
        }
    }
  } else {
#pragma unroll
    for (int j = 0; j < 4; ++j) {
      int n = n0 + wcol + j * 16 + lr;
      float bj = bias[n];
#pragma unroll
      for (int i = 0; i < 4; ++i)
#pragma unroll
        for (int r = 0; r < 4; ++r) {
          int m = m0 + wrow + i * 16 + lq * 4 + r;
          Co[(size_t)m * Nd + n] = acc[i][j][r] + bj;
        }
    }
  }
}

// ---------------------------------------------------------------- RoPE
__global__ __launch_bounds__(256) void rope_kernel(_Float16* __restrict__ Qp,
                                                   _Float16* __restrict__ Kp) {
  int idx = blockIdx.x * 256 + threadIdx.x;  // (qk, bh, t)
  int t = idx & 2047;
  int bh = (idx >> 11) & 63;
  _Float16* base = ((idx >> 17) ? Kp : Qp) + ((size_t)bh * 2048 + t) * 64;
  half8* hp = (half8*)base;
  half8 h0 = hp[0], h1 = hp[1], h2 = hp[2], h3 = hp[3];  // elems 0..31
  float v[32];
#pragma unroll
  for (int j = 0; j < 8; ++j) {
    v[j] = (float)h0[j];      v[8 + j] = (float)h1[j];
    v[16 + j] = (float)h2[j]; v[24 + j] = (float)h3[j];
  }
  float o[32];
#pragma unroll
  for (int j = 0; j < 16; ++j) {
    float freq = __expf(-(float)j * 0.57564627324851148f);
    float ang = (float)t * freq;
    float cs = cosf(ang), sn = sinf(ang);
    o[j] = v[j] * cs - v[j + 16] * sn;
    o[j + 16] = v[j] * sn + v[j + 16] * cs;
  }
  half8 g0, g1, g2, g3;
#pragma unroll
  for (int j = 0; j < 8; ++j) {
    g0[j] = (_Float16)o[j];      g1[j] = (_Float16)o[8 + j];
    g2[j] = (_Float16)o[16 + j]; g3[j] = (_Float16)o[24 + j];
  }
  hp[0] = g0; hp[1] = g1; hp[2] = g2; hp[3] = g3;  // elems 32..63 untouched
}

// ---------------------------------------------------------------- V^T
__global__ __launch_bounds__(256) void vtrans_kernel(const _Float16* __restrict__ V,
                                                     _Float16* __restrict__ Vt) {
  __shared__ __align__(16) _Float16 tile[64][72];
  int s0 = blockIdx.x * 64;
  int bh = blockIdx.y;
  const _Float16* Vb = V + (size_t)bh * 2048 * 64;
  _Float16* Vtb = Vt + (size_t)bh * 64 * 2048;
  int tid = threadIdx.x;
#pragma unroll
  for (int it = 0; it < 2; ++it) {
    int r = (tid >> 3) + it * 32;   // s-local
    int cc = (tid & 7) * 8;         // d
    *(half8*)&tile[r][cc] = *(const half8*)(Vb + (size_t)(s0 + r) * 64 + cc);
  }
  __syncthreads();
#pragma unroll
  for (int it = 0; it < 2; ++it) {
    int r = (tid >> 3) + it * 32;   // d-local
    int cc = (tid & 7) * 8;         // s-local
    half8 o;
#pragma unroll
    for (int j = 0; j < 8; ++j) o[j] = tile[cc + j][r];
    *(half8*)(Vtb + (size_t)r * 2048 + s0 + cc) = o;
  }
}

// ---------------------------------------------------------------- attention
// Flash-style causal attention, S^T formulation.
// Block = (bh, 128-q tile), 4 waves; wave w owns q rows [w*32, w*32+32)
// as 2 column-tiles of the transposed score matrix.
// S^T = mfma(A=K-frag, B=Q-frag): C-layout row=kv=(quad*4+r), col=q=lane&15.
// P^T C-layout == B-operand layout of 16x16x16 MFMA -> PV with P in regs.
__global__ __launch_bounds__(256) void attn_kernel(
    const _Float16* __restrict__ Q, const _Float16* __restrict__ Kk,
    const _Float16* __restrict__ Vt, _Float16* __restrict__ O) {
  constexpr int S = 2048;
  int qt = 15 - (int)blockIdx.x;  // heavy (long) q-tiles dispatch first
  int bh = blockIdx.y;
  int bb = bh >> 5, hh = bh & 31;
  const _Float16* Qb = Q + (size_t)bh * S * 64;
  const _Float16* Kb = Kk + (size_t)bh * S * 64;
  const _Float16* Vb = Vt + (size_t)bh * 64 * S;

  __shared__ __align__(16) _Float16 sK[128 * 72];   // [kv][64+pad], reused as sO
  __shared__ __align__(16) _Float16 sVt[64 * 136];  // [d][128+pad]

  int tid = threadIdx.x, w = tid >> 6, l = tid & 63;
  int lr = l & 15, quad = l >> 4;
  int q0 = qt * 128;

  // Q fragments as B-operand: B[k=d=quad*8+j][n=q=lane&15].
  // scale*log2e folded in (softmax runs in exp2 domain).
  half8 qf[2][2];  // [qtile][ks]
#pragma unroll
  for (int qtl = 0; qtl < 2; ++qtl)
#pragma unroll
    for (int ks = 0; ks < 2; ++ks) {
      half8 v = *(const half8*)(Qb + (size_t)(q0 + w * 32 + qtl * 16 + lr) * 64 +
                                ks * 32 + quad * 8);
      qf[qtl][ks] = v * (_Float16)0.18033688f;  // 0.125 * log2(e)
    }

  floatx4 z4 = {0.f, 0.f, 0.f, 0.f};
  floatx4 Oa[4][2];  // [dt][qtile], C-layout row=d=quad*4+r, col=q=lane&15
  float m_i[2] = {-1e30f, -1e30f}, l_i[2] = {0.f, 0.f};
#pragma unroll
  for (int dt = 0; dt < 4; ++dt)
#pragma unroll
    for (int qtl = 0; qtl < 2; ++qtl) Oa[dt][qtl] = z4;

  for (int jt = 0; jt <= qt; ++jt) {
    int kv0 = jt * 128;
    // stage K tile (128 kv x 64 d) and Vt tile (64 d x 128 kv)
    {
      int rk = tid >> 3, ck = (tid & 7) * 8;
#pragma unroll
      for (int it = 0; it < 4; ++it)
        *(half8*)&sK[(rk + it * 32) * 72 + ck] =
            *(const half8*)(Kb + (size_t)(kv0 + rk + it * 32) * 64 + ck);
      int rv = tid >> 4, cv = (tid & 15) * 8;
#pragma unroll
      for (int it = 0; it < 4; ++it)
        *(half8*)&sVt[(rv + it * 16) * 136 + cv] =
            *(const half8*)(Vb + (size_t)(rv + it * 16) * S + kv0 + cv);
    }
    __syncthreads();

    // S^T = K @ Q^T : rows kv (8 tiles), cols q (2 tiles per wave)
    floatx4 Sa[2][8];  // [qtile][kvt]
#pragma unroll
    for (int qtl = 0; qtl < 2; ++qtl)
#pragma unroll
      for (int kvt = 0; kvt < 8; ++kvt) Sa[qtl][kvt] = z4;
#pragma unroll
    for (int ks = 0; ks < 2; ++ks) {
#pragma unroll
      for (int kvt = 0; kvt < 8; ++kvt) {
        // A-frag: A[m=kv=lane&15][k=d=quad*8+j]
        half8 kf = *(const half8*)&sK[(kvt * 16 + lr) * 72 + ks * 32 + quad * 8];
        Sa[0][kvt] = mfma16(kf, qf[0][ks], Sa[0][kvt]);
        Sa[1][kvt] = mfma16(kf, qf[1][ks], Sa[1][kvt]);
      }
    }

    if (jt == qt) {  // causal mask on diagonal tile: kv_loc > q_loc
#pragma unroll
      for (int qtl = 0; qtl < 2; ++qtl) {
        int q_loc = w * 32 + qtl * 16 + lr;
#pragma unroll
        for (int kvt = 0; kvt < 8; ++kvt) {
          int kv_base = kvt * 16 + quad * 4;
#pragma unroll
          for (int r = 0; r < 4; ++r)
            if (kv_base + r > q_loc) Sa[qtl][kvt][r] = -1e30f;
        }
      }
    }

    // online softmax: per-lane column q, reduce over 32 regs + quads
#pragma unroll
    for (int qtl = 0; qtl < 2; ++qtl) {
      float mx = Sa[qtl][0][0];
#pragma unroll
      for (int kvt = 0; kvt < 8; ++kvt)
#pragma unroll
        for (int r = 0; r < 4; ++r) mx = fmaxf(mx, Sa[qtl][kvt][r]);
      mx = fmaxf(mx, __shfl_xor(mx, 16));
      mx = fmaxf(mx, __shfl_xor(mx, 32));
      float mnew = fmaxf(m_i[qtl], mx);
      float alpha = __builtin_amdgcn_exp2f(m_i[qtl] - mnew);
      m_i[qtl] = mnew;
      float rs = 0.f;
#pragma unroll
      for (int kvt = 0; kvt < 8; ++kvt)
#pragma unroll
        for (int r = 0; r < 4; ++r) {
          float p = __builtin_amdgcn_exp2f(Sa[qtl][kvt][r] - mnew);
          Sa[qtl][kvt][r] = p;
          rs += p;
        }
      rs += __shfl_xor(rs, 16);
      rs += __shfl_xor(rs, 32);
      l_i[qtl] = l_i[qtl] * alpha + rs;
#pragma unroll
      for (int dt = 0; dt < 4; ++dt) Oa[dt][qtl] *= alpha;
    }

    // O^T += V^T @ P^T, K=16 MFMA; P^T already in B-operand layout
#pragma unroll
    for (int kvt = 0; kvt < 8; ++kvt) {
      half4 vf[4];
#pragma unroll
      for (int dt = 0; dt < 4; ++dt)
        // A-frag: A[m=d=lane&15][k=kv=quad*4+j]
        vf[dt] = *(const half4*)&sVt[(dt * 16 + lr) * 136 + kvt * 16 + quad * 4];
      half4 pf[2];
#pragma unroll
      for (int qtl = 0; qtl < 2; ++qtl) {
        pf[qtl][0] = (_Float16)Sa[qtl][kvt][0];
        pf[qtl][1] = (_Float16)Sa[qtl][kvt][1];
        pf[qtl][2] = (_Float16)Sa[qtl][kvt][2];
        pf[qtl][3] = (_Float16)Sa[qtl][kvt][3];
      }
#pragma unroll
      for (int dt = 0; dt < 4; ++dt)
#pragma unroll
        for (int qtl = 0; qtl < 2; ++qtl)
          Oa[dt][qtl] = mfma16k16(vf[dt], pf[qtl], Oa[dt][qtl]);
    }
    __syncthreads();  // also guards sK reuse in epilogue
  }

  // epilogue: O^T -> LDS transpose (reuse sK as sO[q][64+pad]) -> coalesced
  float inv0 = 1.0f / l_i[0], inv1 = 1.0f / l_i[1];
#pragma unroll
  for (int dt = 0; dt < 4; ++dt)
#pragma unroll
    for (int qtl = 0; qtl < 2; ++qtl) {
      float inv = qtl ? inv1 : inv0;
      floatx4 o = Oa[dt][qtl];
      half4 h;
      h[0] = (_Float16)(o[0] * inv); h[1] = (_Float16)(o[1] * inv);
      h[2] = (_Float16)(o[2] * inv); h[3] = (_Float16)(o[3] * inv);
      // q row = w*32+qtl*16+lr ; d = dt*16 + quad*4 + r
      *(half4*)&sK[(w * 32 + qtl * 16 + lr) * 72 + dt * 16 + quad * 4] = h;
    }
  __syncthreads();
#pragma unroll
  for (int it = 0; it < 2; ++it) {
    int row = (tid >> 2) + it * 64;
    int t = q0 + row;
    _Float16* orow = O + ((size_t)(bb * 2048 + t)) * 2048 + hh * 64;
#pragma unroll
    for (int cc = 0; cc < 2; ++cc) {
      int col = (tid & 3) * 16 + cc * 8;
      *(half8*)(orow + col) = *(const half8*)&sK[row * 72 + col];
    }
  }
}

// ---------------------------------------------------------------- launch
extern "C" void kernel_launch(void* const* d_in, const int* in_sizes, int n_in,
                              void* d_out, int out_size, void* d_ws, size_t ws_size,
                              hipStream_t stream) {
  (void)in_sizes; (void)n_in; (void)out_size; (void)ws_size;
  const float* x = (const float*)d_in[0];
  const float* Wqkv = (const float*)d_in[1];
  const float* bqkv = (const float*)d_in[2];
  const float* Wout = (const float*)d_in[3];
  const float* bout = (const float*)d_in[4];
  float* out = (float*)d_out;
  char* ws = (char*)d_ws;

  _Float16* xh    = (_Float16*)(ws + 0);
  _Float16* Vth   = (_Float16*)(ws + 0);          // overlays xh (dead)
  _Float16* wqkvt = (_Float16*)(ws + 16777216);
  _Float16* Oh    = (_Float16*)(ws + 16777216);   // overlays wqkvt (dead)
  _Float16* Qh    = (_Float16*)(ws + 41943040);
  _Float16* Kh    = (_Float16*)(ws + 58720256);
  _Float16* Vh    = (_Float16*)(ws + 75497472);
  _Float16* woutt = (_Float16*)(ws + 92274688);   // total 96 MB

  cvt_x_kernel<<<4096, 256, 0, stream>>>(x, xh);
  cvt_wt_kernel<<<dim3(96, 32), 256, 0, stream>>>(Wqkv, wqkvt, 2048, 6144);
  cvt_wt_kernel<<<dim3(32, 32), 256, 0, stream>>>(Wout, woutt, 2048, 2048);
  gemm_f16_kernel<0><<<dim3(48, 32), 256, 0, stream>>>(
      xh, wqkvt, bqkv, 2048, 6144, Qh, Kh, Vh, nullptr);
  rope_kernel<<<1024, 256, 0, stream>>>(Qh, Kh);
  vtrans_kernel<<<dim3(32, 64), 256, 0, stream>>>(Vh, Vth);
  attn_kernel<<<dim3(16, 64), 256, 0, stream>>>(Qh, Kh, Vth, Oh);
  gemm_f16_kernel<1><<<dim3(16, 32), 256, 0, stream>>>(
      Oh, woutt, bout, 2048, 2048, nullptr, nullptr, nullptr, out);
}

// Round 5
// 445.699 us; speedup vs baseline: 1.3105x; 1.1136x over previous
//
#include <hip/hip_runtime.h>

// MHA fused pipeline for MI355X (gfx950), f16 MFMA + fp32 accumulate.
// Round 5:
//  - gemm: restore global_load_lds width-16 staging (m97 class; round-1 NaN
//    was the attn sV bug, not GLD — swizzle algebra re-verified)
//  - attn: register prefetch of next K/Vt tile issued right after ds_writes
//    (global latency overlaps compute phase instead of sitting on the
//    critical path); grid transposed to (bh, qtrank) so all qt=15 blocks
//    start in the first resident batch
//
// ws layout (bytes):
//   xh     @ 0          : 4096x2048 f16  (x cast)      [dead after gemm<0>]
//   Vth    @ 0          : [64][64][2048] f16 (V^T)     [overlays xh]
//   wqkvt  @ 16777216   : 6144x2048 f16  (Wqkv^T)     [dead after gemm<0>]
//   Oh     @ 16777216   : 4096x2048 f16  (attn out)    [overlays wqkvt]
//   Qh     @ 41943040   : [64 bh][2048][64] f16
//   Kh     @ 58720256   : [64 bh][2048][64] f16
//   Vh     @ 75497472   : [64 bh][2048][64] f16        [dead after vtrans]
//   woutt  @ 92274688   : 2048x2048 f16  (Wout^T)
//   total 100663296 B = 96 MB

typedef _Float16 half8 __attribute__((ext_vector_type(8)));
typedef _Float16 half4 __attribute__((ext_vector_type(4)));
typedef float floatx4 __attribute__((ext_vector_type(4)));

#define GLD_LDS16(gp, sp)                                        \
  __builtin_amdgcn_global_load_lds(                              \
      (__attribute__((address_space(1))) void*)(gp),             \
      (__attribute__((address_space(3))) void*)(sp), 16, 0, 0)

__device__ __forceinline__ floatx4 mfma16(half8 a, half8 b, floatx4 c) {
  return __builtin_amdgcn_mfma_f32_16x16x32_f16(a, b, c, 0, 0, 0);
}
__device__ __forceinline__ floatx4 mfma16k16(half4 a, half4 b, floatx4 c) {
  return __builtin_amdgcn_mfma_f32_16x16x16f16(a, b, c, 0, 0, 0);
}

// ---------------------------------------------------------------- cvt_x
__global__ __launch_bounds__(256) void cvt_x_kernel(const float* __restrict__ x,
                                                    _Float16* __restrict__ xh) {
  int idx = blockIdx.x * 256 + threadIdx.x;  // 8 elems each, 8.4M total
  const floatx4* p = (const floatx4*)x + (size_t)idx * 2;
  floatx4 a = p[0], b = p[1];
  half8 o;
#pragma unroll
  for (int j = 0; j < 4; ++j) { o[j] = (_Float16)a[j]; o[4 + j] = (_Float16)b[j]; }
  *((half8*)xh + idx) = o;
}

// ------------------------------------------------------- cvt + transpose W
// W (Kd x Nd) f32 row-major  ->  Wt (Nd x Kd) f16 row-major
__global__ __launch_bounds__(256) void cvt_wt_kernel(const float* __restrict__ W,
                                                     _Float16* __restrict__ Wt,
                                                     int Kd, int Nd) {
  __shared__ float tile[64][65];
  int n0 = blockIdx.x * 64, k0 = blockIdx.y * 64;
  int tid = threadIdx.x;
#pragma unroll
  for (int it = 0; it < 4; ++it) {
    int r = (tid >> 4) + it * 16;   // k-local
    int c = (tid & 15) * 4;         // n-local
    floatx4 v = *(const floatx4*)(W + (size_t)(k0 + r) * Nd + n0 + c);
    tile[r][c + 0] = v[0]; tile[r][c + 1] = v[1];
    tile[r][c + 2] = v[2]; tile[r][c + 3] = v[3];
  }
  __syncthreads();
#pragma unroll
  for (int it = 0; it < 2; ++it) {
    int r = (tid >> 3) + it * 32;   // n-local
    int c = (tid & 7) * 8;          // k-local
    half8 o;
#pragma unroll
    for (int j = 0; j < 8; ++j) o[j] = (_Float16)tile[c + j][r];
    *(half8*)(Wt + (size_t)(n0 + r) * Kd + k0 + c) = o;
  }
}

// ---------------------------------------------------------------- GEMM
// C(128x128 tile) = A(MxK) @ Bt(NxK)^T + bias.
// Staging via global_load_lds width-16: lane l of wave w fetches global
// k8-chunk slot=(l&7)^(l>>3); HW lands it at (uniform base + l*16B), so LDS
// chunk position p of row r holds global chunk p^(r&7) -> fragment read at
// position ((ks<<2|lq)^(r&7)) yields global chunk (ks<<2|lq). XOR swizzle =
// conflict-free ds_read_b128 without padding (GLD forbids pads).
template <int MODE>
__global__ __launch_bounds__(256) void gemm_f16_kernel(
    const _Float16* __restrict__ A, const _Float16* __restrict__ Bt,
    const float* __restrict__ bias, int Kd, int Nd,
    _Float16* __restrict__ Qd, _Float16* __restrict__ Kkd,
    _Float16* __restrict__ Vd, float* __restrict__ Co) {
  __shared__ __align__(16) _Float16 sA[128 * 64];
  __shared__ __align__(16) _Float16 sB[128 * 64];
  int tid = threadIdx.x, w = tid >> 6, l = tid & 63;
  int lr = l & 15, lq = l >> 4;
  int m0 = blockIdx.y * 128, n0 = blockIdx.x * 128;
  int wrow = (w >> 1) * 64, wcol = (w & 1) * 64;

  floatx4 z4 = {0.f, 0.f, 0.f, 0.f};
  floatx4 acc[4][4];
#pragma unroll
  for (int i = 0; i < 4; ++i)
#pragma unroll
    for (int j = 0; j < 4; ++j) acc[i][j] = z4;

  // staging: wave w covers rows [w*32, w*32+32) (4 chunks x 8 rows)
  int srow = l >> 3;              // row within 8-row chunk
  int slot = (l & 7) ^ srow;      // XOR-swizzled global k8-chunk
  const _Float16* aG = A + (size_t)(m0 + w * 32 + srow) * Kd + slot * 8;
  const _Float16* bG = Bt + (size_t)(n0 + w * 32 + srow) * Kd + slot * 8;
  _Float16* sAw = &sA[w * 2048];
  _Float16* sBw = &sB[w * 2048];

  for (int kt = 0; kt < Kd; kt += 64) {
#pragma unroll
    for (int t = 0; t < 4; ++t) {
      GLD_LDS16(aG + (size_t)t * 8 * Kd + kt, sAw + t * 512);
      GLD_LDS16(bG + (size_t)t * 8 * Kd + kt, sBw + t * 512);
    }
    __syncthreads();
#pragma unroll
    for (int ks = 0; ks < 2; ++ks) {
      half8 af[4], bf[4];
#pragma unroll
      for (int i = 0; i < 4; ++i) {
        int ar = wrow + i * 16 + lr;
        int br = wcol + i * 16 + lr;
        int sl = (((ks << 2) | lq) ^ (lr & 7)) * 8;  // row&7 == lr&7
        af[i] = *(const half8*)&sA[ar * 64 + sl];
        bf[i] = *(const half8*)&sB[br * 64 + sl];
      }
#pragma unroll
      for (int i = 0; i < 4; ++i)
#pragma unroll
        for (int j = 0; j < 4; ++j) acc[i][j] = mfma16(af[i], bf[j], acc[i][j]);
    }
    __syncthreads();
  }

  // epilogue: C/D layout col = lane&15, row = (lane>>4)*4 + reg (m89/m91)
  if (MODE == 0) {
    int which = n0 >> 11;  // 0:q 1:k 2:v, uniform per block
    _Float16* dst = (which == 0) ? Qd : (which == 1) ? Kkd : Vd;
#pragma unroll
    for (int j = 0; j < 4; ++j) {
      int n = n0 + wcol + j * 16 + lr;
      float bj = bias[n];
      int hh = (n & 2047) >> 6, dd = n & 63;
#pragma unroll
      for (int i = 0; i < 4; ++i)
#pragma unroll
        for (int r = 0; r < 4; ++r) {
          int m = m0 + wrow + i * 16 + lq * 4 + r;
          int bb = m >> 11, t = m & 2047;
          dst[((size_t)(bb * 32 + hh) * 2048 + (size_t)t) * 64 + dd] =
              (_Float16)(acc[i][j][r] + bj);
        }
    }
  } else {
#pragma unroll
    for (int j = 0; j < 4; ++j) {
      int n = n0 + wcol + j * 16 + lr;
      float bj = bias[n];
#pragma unroll
      for (int i = 0; i < 4; ++i)
#pragma unroll
        for (int r = 0; r < 4; ++r) {
          int m = m0 + wrow + i * 16 + lq * 4 + r;
          Co[(size_t)m * Nd + n] = acc[i][j][r] + bj;
        }
    }
  }
}

// ---------------------------------------------------------------- RoPE
__global__ __launch_bounds__(256) void rope_kernel(_Float16* __restrict__ Qp,
                                                   _Float16* __restrict__ Kp) {
  int idx = blockIdx.x * 256 + threadIdx.x;  // (qk, bh, t)
  int t = idx & 2047;
  int bh = (idx >> 11) & 63;
  _Float16* base = ((idx >> 17) ? Kp : Qp) + ((size_t)bh * 2048 + t) * 64;
  half8* hp = (half8*)base;
  half8 h0 = hp[0], h1 = hp[1], h2 = hp[2], h3 = hp[3];  // elems 0..31
  float v[32];
#pragma unroll
  for (int j = 0; j < 8; ++j) {
    v[j] = (float)h0[j];      v[8 + j] = (float)h1[j];
    v[16 + j] = (float)h2[j]; v[24 + j] = (float)h3[j];
  }
  float o[32];
#pragma unroll
  for (int j = 0; j < 16; ++j) {
    float freq = __expf(-(float)j * 0.57564627324851148f);
    float ang = (float)t * freq;
    float cs = cosf(ang), sn = sinf(ang);
    o[j] = v[j] * cs - v[j + 16] * sn;
    o[j + 16] = v[j] * sn + v[j + 16] * cs;
  }
  half8 g0, g1, g2, g3;
#pragma unroll
  for (int j = 0; j < 8; ++j) {
    g0[j] = (_Float16)o[j];      g1[j] = (_Float16)o[8 + j];
    g2[j] = (_Float16)o[16 + j]; g3[j] = (_Float16)o[24 + j];
  }
  hp[0] = g0; hp[1] = g1; hp[2] = g2; hp[3] = g3;  // elems 32..63 untouched
}

// ---------------------------------------------------------------- V^T
__global__ __launch_bounds__(256) void vtrans_kernel(const _Float16* __restrict__ V,
                                                     _Float16* __restrict__ Vt) {
  __shared__ __align__(16) _Float16 tile[64][72];
  int s0 = blockIdx.x * 64;
  int bh = blockIdx.y;
  const _Float16* Vb = V + (size_t)bh * 2048 * 64;
  _Float16* Vtb = Vt + (size_t)bh * 64 * 2048;
  int tid = threadIdx.x;
#pragma unroll
  for (int it = 0; it < 2; ++it) {
    int r = (tid >> 3) + it * 32;   // s-local
    int cc = (tid & 7) * 8;         // d
    *(half8*)&tile[r][cc] = *(const half8*)(Vb + (size_t)(s0 + r) * 64 + cc);
  }
  __syncthreads();
#pragma unroll
  for (int it = 0; it < 2; ++it) {
    int r = (tid >> 3) + it * 32;   // d-local
    int cc = (tid & 7) * 8;         // s-local
    half8 o;
#pragma unroll
    for (int j = 0; j < 8; ++j) o[j] = tile[cc + j][r];
    *(half8*)(Vtb + (size_t)r * 2048 + s0 + cc) = o;
  }
}

// ---------------------------------------------------------------- attention
// Flash-style causal attention, S^T formulation + register prefetch.
// Block = (bh, 128-q tile), 4 waves; wave w owns q rows [w*32, w*32+32).
// S^T = mfma(A=K-frag, B=Q-frag): C-layout row=kv, col=q=lane&15.
// P^T C-layout == B-operand layout of 16x16x16 MFMA -> PV with P in regs.
// Next kv-tile's K/Vt are loaded to registers during the compute phase.
__global__ __launch_bounds__(256, 3) void attn_kernel(
    const _Float16* __restrict__ Q, const _Float16* __restrict__ Kk,
    const _Float16* __restrict__ Vt, _Float16* __restrict__ O) {
  constexpr int S = 2048;
  int bh = blockIdx.x;
  int qt = 15 - (int)blockIdx.y;  // all heavy q-tiles in the first batch
  int bb = bh >> 5, hh = bh & 31;
  const _Float16* Qb = Q + (size_t)bh * S * 64;
  const _Float16* Kb = Kk + (size_t)bh * S * 64;
  const _Float16* Vb = Vt + (size_t)bh * 64 * S;

  __shared__ __align__(16) _Float16 sK[128 * 72];   // [kv][64+pad], reused as sO
  __shared__ __align__(16) _Float16 sVt[64 * 136];  // [d][128+pad]

  int tid = threadIdx.x, w = tid >> 6, l = tid & 63;
  int lr = l & 15, quad = l >> 4;
  int q0 = qt * 128;

  // Q fragments as B-operand: B[k=d=quad*8+j][n=q=lane&15]; scale*log2e folded.
  half8 qf[2][2];  // [qtile][ks]
#pragma unroll
  for (int qtl = 0; qtl < 2; ++qtl)
#pragma unroll
    for (int ks = 0; ks < 2; ++ks) {
      half8 v = *(const half8*)(Qb + (size_t)(q0 + w * 32 + qtl * 16 + lr) * 64 +
                                ks * 32 + quad * 8);
      qf[qtl][ks] = v * (_Float16)0.18033688f;  // 0.125 * log2(e)
    }

  floatx4 z4 = {0.f, 0.f, 0.f, 0.f};
  floatx4 Oa[4][2];  // [dt][qtile], C-layout row=d=quad*4+r, col=q=lane&15
  float m_i[2] = {-1e30f, -1e30f}, l_i[2] = {0.f, 0.f};
#pragma unroll
  for (int dt = 0; dt < 4; ++dt)
#pragma unroll
    for (int qtl = 0; qtl < 2; ++qtl) Oa[dt][qtl] = z4;

  // staging lane geometry + prefetch of tile jt=0
  int rk = tid >> 3, ck = (tid & 7) * 8;   // K: 32 rows x 64d per pass
  int rv = tid >> 4, cv = (tid & 15) * 8;  // Vt: 16 rows x 128kv per pass
  const _Float16* Kst = Kb + (size_t)rk * 64 + ck;
  const _Float16* Vst = Vb + (size_t)rv * S + cv;
  half8 kpre[4], vpre[4];
#pragma unroll
  for (int it = 0; it < 4; ++it) {
    kpre[it] = *(const half8*)(Kst + (size_t)it * 32 * 64);
    vpre[it] = *(const half8*)(Vst + (size_t)it * 16 * S);
  }

  for (int jt = 0; jt <= qt; ++jt) {
    // commit prefetched tile to LDS
#pragma unroll
    for (int it = 0; it < 4; ++it) {
      *(half8*)&sK[(rk + it * 32) * 72 + ck] = kpre[it];
      *(half8*)&sVt[(rv + it * 16) * 136 + cv] = vpre[it];
    }
    // issue next tile's loads; they fly during this iteration's compute
    if (jt < qt) {
      int kv1 = (jt + 1) * 128;
#pragma unroll
      for (int it = 0; it < 4; ++it) {
        kpre[it] = *(const half8*)(Kst + (size_t)(kv1 + it * 32) * 64);
        vpre[it] = *(const half8*)(Vst + kv1 + (size_t)it * 16 * S);
      }
    }
    __syncthreads();

    // S^T = K @ Q^T : rows kv (8 tiles), cols q (2 tiles per wave)
    floatx4 Sa[2][8];  // [qtile][kvt]
#pragma unroll
    for (int qtl = 0; qtl < 2; ++qtl)
#pragma unroll
      for (int kvt = 0; kvt < 8; ++kvt) Sa[qtl][kvt] = z4;
#pragma unroll
    for (int ks = 0; ks < 2; ++ks) {
#pragma unroll
      for (int kvt = 0; kvt < 8; ++kvt) {
        // A-frag: A[m=kv=lane&15][k=d=quad*8+j]
        half8 kf = *(const half8*)&sK[(kvt * 16 + lr) * 72 + ks * 32 + quad * 8];
        Sa[0][kvt] = mfma16(kf, qf[0][ks], Sa[0][kvt]);
        Sa[1][kvt] = mfma16(kf, qf[1][ks], Sa[1][kvt]);
      }
    }

    if (jt == qt) {  // causal mask on diagonal tile: kv_loc > q_loc
#pragma unroll
      for (int qtl = 0; qtl < 2; ++qtl) {
        int q_loc = w * 32 + qtl * 16 + lr;
#pragma unroll
        for (int kvt = 0; kvt < 8; ++kvt) {
          int kv_base = kvt * 16 + quad * 4;
#pragma unroll
          for (int r = 0; r < 4; ++r)
            if (kv_base + r > q_loc) Sa[qtl][kvt][r] = -1e30f;
        }
      }
    }

    // online softmax: per-lane column q, reduce over 32 regs + 2 shuffles
#pragma unroll
    for (int qtl = 0; qtl < 2; ++qtl) {
      float mx = Sa[qtl][0][0];
#pragma unroll
      for (int kvt = 0; kvt < 8; ++kvt)
#pragma unroll
        for (int r = 0; r < 4; ++r) mx = fmaxf(mx, Sa[qtl][kvt][r]);
      mx = fmaxf(mx, __shfl_xor(mx, 16));
      mx = fmaxf(mx, __shfl_xor(mx, 32));
      float mnew = fmaxf(m_i[qtl], mx);
      float alpha = __builtin_amdgcn_exp2f(m_i[qtl] - mnew);
      m_i[qtl] = mnew;
      float rs = 0.f;
#pragma unroll
      for (int kvt = 0; kvt < 8; ++kvt)
#pragma unroll
        for (int r = 0; r < 4; ++r) {
          float p = __builtin_amdgcn_exp2f(Sa[qtl][kvt][r] - mnew);
          Sa[qtl][kvt][r] = p;
          rs += p;
        }
      rs += __shfl_xor(rs, 16);
      rs += __shfl_xor(rs, 32);
      l_i[qtl] = l_i[qtl] * alpha + rs;
#pragma unroll
      for (int dt = 0; dt < 4; ++dt) Oa[dt][qtl] *= alpha;
    }

    // O^T += V^T @ P^T, K=16 MFMA; P^T already in B-operand layout
#pragma unroll
    for (int kvt = 0; kvt < 8; ++kvt) {
      half4 vf[4];
#pragma unroll
      for (int dt = 0; dt < 4; ++dt)
        // A-frag: A[m=d=lane&15][k=kv=quad*4+j]
        vf[dt] = *(const half4*)&sVt[(dt * 16 + lr) * 136 + kvt * 16 + quad * 4];
      half4 pf[2];
#pragma unroll
      for (int qtl = 0; qtl < 2; ++qtl) {
        pf[qtl][0] = (_Float16)Sa[qtl][kvt][0];
        pf[qtl][1] = (_Float16)Sa[qtl][kvt][1];
        pf[qtl][2] = (_Float16)Sa[qtl][kvt][2];
        pf[qtl][3] = (_Float16)Sa[qtl][kvt][3];
      }
#pragma unroll
      for (int dt = 0; dt < 4; ++dt)
#pragma unroll
        for (int qtl = 0; qtl < 2; ++qtl)
          Oa[dt][qtl] = mfma16k16(vf[dt], pf[qtl], Oa[dt][qtl]);
    }
    __syncthreads();  // LDS reads done before next iteration's ds_writes
  }

  // epilogue: O^T -> LDS transpose (reuse sK as sO[q][64+pad]) -> coalesced
  float inv0 = 1.0f / l_i[0], inv1 = 1.0f / l_i[1];
#pragma unroll
  for (int dt = 0; dt < 4; ++dt)
#pragma unroll
    for (int qtl = 0; qtl < 2; ++qtl) {
      float inv = qtl ? inv1 : inv0;
      floatx4 o = Oa[dt][qtl];
      half4 h;
      h[0] = (_Float16)(o[0] * inv); h[1] = (_Float16)(o[1] * inv);
      h[2] = (_Float16)(o[2] * inv); h[3] = (_Float16)(o[3] * inv);
      // q row = w*32+qtl*16+lr ; d = dt*16 + quad*4 + r
      *(half4*)&sK[(w * 32 + qtl * 16 + lr) * 72 + dt * 16 + quad * 4] = h;
    }
  __syncthreads();
#pragma unroll
  for (int it = 0; it < 2; ++it) {
    int row = (tid >> 2) + it * 64;
    int t = q0 + row;
    _Float16* orow = O + ((size_t)(bb * 2048 + t)) * 2048 + hh * 64;
#pragma unroll
    for (int cc = 0; cc < 2; ++cc) {
      int col = (tid & 3) * 16 + cc * 8;
      *(half8*)(orow + col) = *(const half8*)&sK[row * 72 + col];
    }
  }
}

// ---------------------------------------------------------------- launch
extern "C" void kernel_launch(void* const* d_in, const int* in_sizes, int n_in,
                              void* d_out, int out_size, void* d_ws, size_t ws_size,
                              hipStream_t stream) {
  (void)in_sizes; (void)n_in; (void)out_size; (void)ws_size;
  const float* x = (const float*)d_in[0];
  const float* Wqkv = (const float*)d_in[1];
  const float* bqkv = (const float*)d_in[2];
  const float* Wout = (const float*)d_in[3];
  const float* bout = (const float*)d_in[4];
  float* out = (float*)d_out;
  char* ws = (char*)d_ws;

  _Float16* xh    = (_Float16*)(ws + 0);
  _Float16* Vth   = (_Float16*)(ws + 0);          // overlays xh (dead)
  _Float16* wqkvt = (_Float16*)(ws + 16777216);
  _Float16* Oh    = (_Float16*)(ws + 16777216);   // overlays wqkvt (dead)
  _Float16* Qh    = (_Float16*)(ws + 41943040);
  _Float16* Kh    = (_Float16*)(ws + 58720256);
  _Float16* Vh    = (_Float16*)(ws + 75497472);
  _Float16* woutt = (_Float16*)(ws + 92274688);   // total 96 MB

  cvt_x_kernel<<<4096, 256, 0, stream>>>(x, xh);
  cvt_wt_kernel<<<dim3(96, 32), 256, 0, stream>>>(Wqkv, wqkvt, 2048, 6144);
  cvt_wt_kernel<<<dim3(32, 32), 256, 0, stream>>>(Wout, woutt, 2048, 2048);
  gemm_f16_kernel<0><<<dim3(48, 32), 256, 0, stream>>>(
      xh, wqkvt, bqkv, 2048, 6144, Qh, Kh, Vh, nullptr);
  rope_kernel<<<1024, 256, 0, stream>>>(Qh, Kh);
  vtrans_kernel<<<dim3(32, 64), 256, 0, stream>>>(Vh, Vth);
  attn_kernel<<<dim3(64, 16), 256, 0, stream>>>(Qh, Kh, Vth, Oh);
  gemm_f16_kernel<1><<<dim3(16, 32), 256, 0, stream>>>(
      Oh, woutt, bout, 2048, 2048, nullptr, nullptr, nullptr, out);
}

// Round 6
// 432.914 us; speedup vs baseline: 1.3492x; 1.0295x over previous
//
#include <hip/hip_runtime.h>

// MHA fused pipeline for MI355X (gfx950), f16 MFMA + fp32 accumulate.
// Round 6: fuse RoPE and the V^T transpose into the gemm<0> epilogue.
//  - RoPE pair (d, d+16) for d<16 = acc[i][0] / acc[i][1] of the SAME lane
//    (lane's j-tiles hold d = lr, lr+16, lr+32, lr+48) -> in-register rotate,
//    one freq per lane, 16 sincosf per lane, bias added before rotation.
//    rope_kernel deleted (+67 MB HBM round-trip gone).
//  - V blocks: acc[i][j][0..3] = 4 consecutive t at fixed d -> half4 store
//    straight into V^T [bh][d][s] (4-lane 32B runs, lines filled across i).
//    vtrans_kernel deleted.
//
// ws layout (bytes):
//   xh     @ 0          : 4096x2048 f16  (x cast)     [read by gemm<0>]
//   wqkvt  @ 16777216   : 6144x2048 f16  (Wqkv^T)    [dead after gemm<0>]
//   Oh     @ 16777216   : 4096x2048 f16  (attn out)   [overlays wqkvt]
//   Qh     @ 41943040   : [64 bh][2048][64] f16  (RoPE'd)
//   Kh     @ 58720256   : [64 bh][2048][64] f16  (RoPE'd)
//   Vth    @ 75497472   : [64 bh][64][2048] f16  (V^T, written by gemm<0>)
//   woutt  @ 92274688   : 2048x2048 f16  (Wout^T)
//   total 100663296 B = 96 MB

typedef _Float16 half8 __attribute__((ext_vector_type(8)));
typedef _Float16 half4 __attribute__((ext_vector_type(4)));
typedef float floatx4 __attribute__((ext_vector_type(4)));

#define GLD_LDS16(gp, sp)                                        \
  __builtin_amdgcn_global_load_lds(                              \
      (__attribute__((address_space(1))) void*)(gp),             \
      (__attribute__((address_space(3))) void*)(sp), 16, 0, 0)

__device__ __forceinline__ floatx4 mfma16(half8 a, half8 b, floatx4 c) {
  return __builtin_amdgcn_mfma_f32_16x16x32_f16(a, b, c, 0, 0, 0);
}
__device__ __forceinline__ floatx4 mfma16k16(half4 a, half4 b, floatx4 c) {
  return __builtin_amdgcn_mfma_f32_16x16x16f16(a, b, c, 0, 0, 0);
}

// ---------------------------------------------------------------- cvt_x
__global__ __launch_bounds__(256) void cvt_x_kernel(const float* __restrict__ x,
                                                    _Float16* __restrict__ xh) {
  int idx = blockIdx.x * 256 + threadIdx.x;  // 8 elems each, 8.4M total
  const floatx4* p = (const floatx4*)x + (size_t)idx * 2;
  floatx4 a = p[0], b = p[1];
  half8 o;
#pragma unroll
  for (int j = 0; j < 4; ++j) { o[j] = (_Float16)a[j]; o[4 + j] = (_Float16)b[j]; }
  *((half8*)xh + idx) = o;
}

// ------------------------------------------------------- cvt + transpose W
// W (Kd x Nd) f32 row-major  ->  Wt (Nd x Kd) f16 row-major
__global__ __launch_bounds__(256) void cvt_wt_kernel(const float* __restrict__ W,
                                                     _Float16* __restrict__ Wt,
                                                     int Kd, int Nd) {
  __shared__ float tile[64][65];
  int n0 = blockIdx.x * 64, k0 = blockIdx.y * 64;
  int tid = threadIdx.x;
#pragma unroll
  for (int it = 0; it < 4; ++it) {
    int r = (tid >> 4) + it * 16;   // k-local
    int c = (tid & 15) * 4;         // n-local
    floatx4 v = *(const floatx4*)(W + (size_t)(k0 + r) * Nd + n0 + c);
    tile[r][c + 0] = v[0]; tile[r][c + 1] = v[1];
    tile[r][c + 2] = v[2]; tile[r][c + 3] = v[3];
  }
  __syncthreads();
#pragma unroll
  for (int it = 0; it < 2; ++it) {
    int r = (tid >> 3) + it * 32;   // n-local
    int c = (tid & 7) * 8;          // k-local
    half8 o;
#pragma unroll
    for (int j = 0; j < 8; ++j) o[j] = (_Float16)tile[c + j][r];
    *(half8*)(Wt + (size_t)(n0 + r) * Kd + k0 + c) = o;
  }
}

// ---------------------------------------------------------------- GEMM
// C(128x128 tile) = A(MxK) @ Bt(NxK)^T + bias.
// MODE 0 epilogue: q/k blocks -> bias + in-register RoPE -> [bh][s][64];
//                  v blocks   -> bias + direct V^T [bh][d][s] half4 stores.
// MODE 1 epilogue: fp32 Co[m*Nd+n] + bias.
// Staging via global_load_lds width-16 + XOR swizzle (round-5, verified).
template <int MODE>
__global__ __launch_bounds__(256) void gemm_f16_kernel(
    const _Float16* __restrict__ A, const _Float16* __restrict__ Bt,
    const float* __restrict__ bias, int Kd, int Nd,
    _Float16* __restrict__ Qd, _Float16* __restrict__ Kkd,
    _Float16* __restrict__ Vd, float* __restrict__ Co) {
  __shared__ __align__(16) _Float16 sA[128 * 64];
  __shared__ __align__(16) _Float16 sB[128 * 64];
  int tid = threadIdx.x, w = tid >> 6, l = tid & 63;
  int lr = l & 15, lq = l >> 4;
  int m0 = blockIdx.y * 128, n0 = blockIdx.x * 128;
  int wrow = (w >> 1) * 64, wcol = (w & 1) * 64;

  floatx4 z4 = {0.f, 0.f, 0.f, 0.f};
  floatx4 acc[4][4];
#pragma unroll
  for (int i = 0; i < 4; ++i)
#pragma unroll
    for (int j = 0; j < 4; ++j) acc[i][j] = z4;

  // staging: wave w covers rows [w*32, w*32+32) (4 chunks x 8 rows)
  int srow = l >> 3;              // row within 8-row chunk
  int slot = (l & 7) ^ srow;      // XOR-swizzled global k8-chunk
  const _Float16* aG = A + (size_t)(m0 + w * 32 + srow) * Kd + slot * 8;
  const _Float16* bG = Bt + (size_t)(n0 + w * 32 + srow) * Kd + slot * 8;
  _Float16* sAw = &sA[w * 2048];
  _Float16* sBw = &sB[w * 2048];

  for (int kt = 0; kt < Kd; kt += 64) {
#pragma unroll
    for (int t = 0; t < 4; ++t) {
      GLD_LDS16(aG + (size_t)t * 8 * Kd + kt, sAw + t * 512);
      GLD_LDS16(bG + (size_t)t * 8 * Kd + kt, sBw + t * 512);
    }
    __syncthreads();
#pragma unroll
    for (int ks = 0; ks < 2; ++ks) {
      half8 af[4], bf[4];
#pragma unroll
      for (int i = 0; i < 4; ++i) {
        int ar = wrow + i * 16 + lr;
        int br = wcol + i * 16 + lr;
        int sl = (((ks << 2) | lq) ^ (lr & 7)) * 8;  // row&7 == lr&7
        af[i] = *(const half8*)&sA[ar * 64 + sl];
        bf[i] = *(const half8*)&sB[br * 64 + sl];
      }
#pragma unroll
      for (int i = 0; i < 4; ++i)
#pragma unroll
        for (int j = 0; j < 4; ++j) acc[i][j] = mfma16(af[i], bf[j], acc[i][j]);
    }
    __syncthreads();
  }

  // epilogue. C/D layout: col = lane&15, row = (lane>>4)*4 + reg (m89/m91).
  // Lane's 4 j-tiles hold d = lr, lr+16, lr+32, lr+48 within one head:
  // dd = j*16+lr, hh = ((n0&2047)+wcol)>>6 (uniform over j for this lane).
  if (MODE == 0) {
    int which = n0 >> 11;  // 0:q 1:k 2:v, uniform per block
    float bj[4];
#pragma unroll
    for (int j = 0; j < 4; ++j) bj[j] = bias[n0 + wcol + j * 16 + lr];
    int hh = ((n0 & 2047) + wcol) >> 6;
    if (which == 2) {
      // V^T: acc[i][j][r] -> Vd[bh][d=j*16+lr][t..t+3], half4 runs
#pragma unroll
      for (int j = 0; j < 4; ++j) {
        int dd = j * 16 + lr;
#pragma unroll
        for (int i = 0; i < 4; ++i) {
          int m = m0 + wrow + i * 16 + lq * 4;
          int bb = m >> 11, t = m & 2047;
          half4 h;
#pragma unroll
          for (int r = 0; r < 4; ++r) h[r] = (_Float16)(acc[i][j][r] + bj[j]);
          *(half4*)&Vd[(((size_t)(bb * 32 + hh)) * 64 + dd) * 2048 + t] = h;
        }
      }
    } else {
      _Float16* dst = which ? Kkd : Qd;
      // RoPE: pair (d=lr, d=lr+16) = (acc[i][0], acc[i][1]); freq per lane
      float freq = __expf(-(float)lr * 0.57564627324851148f);  // 10000^(-lr/16)
#pragma unroll
      for (int i = 0; i < 4; ++i)
#pragma unroll
        for (int r = 0; r < 4; ++r) {
          int m = m0 + wrow + i * 16 + lq * 4 + r;
          int bb = m >> 11, t = m & 2047;
          float sn, cs;
          sincosf((float)t * freq, &sn, &cs);
          float x1 = acc[i][0][r] + bj[0];
          float x2 = acc[i][1][r] + bj[1];
          _Float16* row = dst + ((size_t)(bb * 32 + hh) * 2048 + (size_t)t) * 64;
          row[lr]      = (_Float16)(x1 * cs - x2 * sn);
          row[lr + 16] = (_Float16)(x1 * sn + x2 * cs);
          row[lr + 32] = (_Float16)(acc[i][2][r] + bj[2]);
          row[lr + 48] = (_Float16)(acc[i][3][r] + bj[3]);
        }
    }
  } else {
#pragma unroll
    for (int j = 0; j < 4; ++j) {
      int n = n0 + wcol + j * 16 + lr;
      float bj = bias[n];
#pragma unroll
      for (int i = 0; i < 4; ++i)
#pragma unroll
        for (int r = 0; r < 4; ++r) {
          int m = m0 + wrow + i * 16 + lq * 4 + r;
          Co[(size_t)m * Nd + n] = acc[i][j][r] + bj;
        }
    }
  }
}

// ---------------------------------------------------------------- attention
// Flash-style causal attention, S^T formulation + register prefetch.
// (unchanged from round 5)
__global__ __launch_bounds__(256, 3) void attn_kernel(
    const _Float16* __restrict__ Q, const _Float16* __restrict__ Kk,
    const _Float16* __restrict__ Vt, _Float16* __restrict__ O) {
  constexpr int S = 2048;
  int bh = blockIdx.x;
  int qt = 15 - (int)blockIdx.y;  // all heavy q-tiles in the first batch
  int bb = bh >> 5, hh = bh & 31;
  const _Float16* Qb = Q + (size_t)bh * S * 64;
  const _Float16* Kb = Kk + (size_t)bh * S * 64;
  const _Float16* Vb = Vt + (size_t)bh * 64 * S;

  __shared__ __align__(16) _Float16 sK[128 * 72];   // [kv][64+pad], reused as sO
  __shared__ __align__(16) _Float16 sVt[64 * 136];  // [d][128+pad]

  int tid = threadIdx.x, w = tid >> 6, l = tid & 63;
  int lr = l & 15, quad = l >> 4;
  int q0 = qt * 128;

  // Q fragments as B-operand: B[k=d=quad*8+j][n=q=lane&15]; scale*log2e folded.
  half8 qf[2][2];  // [qtile][ks]
#pragma unroll
  for (int qtl = 0; qtl < 2; ++qtl)
#pragma unroll
    for (int ks = 0; ks < 2; ++ks) {
      half8 v = *(const half8*)(Qb + (size_t)(q0 + w * 32 + qtl * 16 + lr) * 64 +
                                ks * 32 + quad * 8);
      qf[qtl][ks] = v * (_Float16)0.18033688f;  // 0.125 * log2(e)
    }

  floatx4 z4 = {0.f, 0.f, 0.f, 0.f};
  floatx4 Oa[4][2];  // [dt][qtile], C-layout row=d=quad*4+r, col=q=lane&15
  float m_i[2] = {-1e30f, -1e30f}, l_i[2] = {0.f, 0.f};
#pragma unroll
  for (int dt = 0; dt < 4; ++dt)
#pragma unroll
    for (int qtl = 0; qtl < 2; ++qtl) Oa[dt][qtl] = z4;

  // staging lane geometry + prefetch of tile jt=0
  int rk = tid >> 3, ck = (tid & 7) * 8;   // K: 32 rows x 64d per pass
  int rv = tid >> 4, cv = (tid & 15) * 8;  // Vt: 16 rows x 128kv per pass
  const _Float16* Kst = Kb + (size_t)rk * 64 + ck;
  const _Float16* Vst = Vb + (size_t)rv * S + cv;
  half8 kpre[4], vpre[4];
#pragma unroll
  for (int it = 0; it < 4; ++it) {
    kpre[it] = *(const half8*)(Kst + (size_t)it * 32 * 64);
    vpre[it] = *(const half8*)(Vst + (size_t)it * 16 * S);
  }

  for (int jt = 0; jt <= qt; ++jt) {
    // commit prefetched tile to LDS
#pragma unroll
    for (int it = 0; it < 4; ++it) {
      *(half8*)&sK[(rk + it * 32) * 72 + ck] = kpre[it];
      *(half8*)&sVt[(rv + it * 16) * 136 + cv] = vpre[it];
    }
    // issue next tile's loads; they fly during this iteration's compute
    if (jt < qt) {
      int kv1 = (jt + 1) * 128;
#pragma unroll
      for (int it = 0; it < 4; ++it) {
        kpre[it] = *(const half8*)(Kst + (size_t)(kv1 + it * 32) * 64);
        vpre[it] = *(const half8*)(Vst + kv1 + (size_t)it * 16 * S);
      }
    }
    __syncthreads();

    // S^T = K @ Q^T : rows kv (8 tiles), cols q (2 tiles per wave)
    floatx4 Sa[2][8];  // [qtile][kvt]
#pragma unroll
    for (int qtl = 0; qtl < 2; ++qtl)
#pragma unroll
      for (int kvt = 0; kvt < 8; ++kvt) Sa[qtl][kvt] = z4;
#pragma unroll
    for (int ks = 0; ks < 2; ++ks) {
#pragma unroll
      for (int kvt = 0; kvt < 8; ++kvt) {
        // A-frag: A[m=kv=lane&15][k=d=quad*8+j]
        half8 kf = *(const half8*)&sK[(kvt * 16 + lr) * 72 + ks * 32 + quad * 8];
        Sa[0][kvt] = mfma16(kf, qf[0][ks], Sa[0][kvt]);
        Sa[1][kvt] = mfma16(kf, qf[1][ks], Sa[1][kvt]);
      }
    }

    if (jt == qt) {  // causal mask on diagonal tile: kv_loc > q_loc
#pragma unroll
      for (int qtl = 0; qtl < 2; ++qtl) {
        int q_loc = w * 32 + qtl * 16 + lr;
#pragma unroll
        for (int kvt = 0; kvt < 8; ++kvt) {
          int kv_base = kvt * 16 + quad * 4;
#pragma unroll
          for (int r = 0; r < 4; ++r)
            if (kv_base + r > q_loc) Sa[qtl][kvt][r] = -1e30f;
        }
      }
    }

    // online softmax: per-lane column q, reduce over 32 regs + 2 shuffles
#pragma unroll
    for (int qtl = 0; qtl < 2; ++qtl) {
      float mx = Sa[qtl][0][0];
#pragma unroll
      for (int kvt = 0; kvt < 8; ++kvt)
#pragma unroll
        for (int r = 0; r < 4; ++r) mx = fmaxf(mx, Sa[qtl][kvt][r]);
      mx = fmaxf(mx, __shfl_xor(mx, 16));
      mx = fmaxf(mx, __shfl_xor(mx, 32));
      float mnew = fmaxf(m_i[qtl], mx);
      float alpha = __builtin_amdgcn_exp2f(m_i[qtl] - mnew);
      m_i[qtl] = mnew;
      float rs = 0.f;
#pragma unroll
      for (int kvt = 0; kvt < 8; ++kvt)
#pragma unroll
        for (int r = 0; r < 4; ++r) {
          float p = __builtin_amdgcn_exp2f(Sa[qtl][kvt][r] - mnew);
          Sa[qtl][kvt][r] = p;
          rs += p;
        }
      rs += __shfl_xor(rs, 16);
      rs += __shfl_xor(rs, 32);
      l_i[qtl] = l_i[qtl] * alpha + rs;
#pragma unroll
      for (int dt = 0; dt < 4; ++dt) Oa[dt][qtl] *= alpha;
    }

    // O^T += V^T @ P^T, K=16 MFMA; P^T already in B-operand layout
#pragma unroll
    for (int kvt = 0; kvt < 8; ++kvt) {
      half4 vf[4];
#pragma unroll
      for (int dt = 0; dt < 4; ++dt)
        // A-frag: A[m=d=lane&15][k=kv=quad*4+j]
        vf[dt] = *(const half4*)&sVt[(dt * 16 + lr) * 136 + kvt * 16 + quad * 4];
      half4 pf[2];
#pragma unroll
      for (int qtl = 0; qtl < 2; ++qtl) {
        pf[qtl][0] = (_Float16)Sa[qtl][kvt][0];
        pf[qtl][1] = (_Float16)Sa[qtl][kvt][1];
        pf[qtl][2] = (_Float16)Sa[qtl][kvt][2];
        pf[qtl][3] = (_Float16)Sa[qtl][kvt][3];
      }
#pragma unroll
      for (int dt = 0; dt < 4; ++dt)
#pragma unroll
        for (int qtl = 0; qtl < 2; ++qtl)
          Oa[dt][qtl] = mfma16k16(vf[dt], pf[qtl], Oa[dt][qtl]);
    }
    __syncthreads();  // LDS reads done before next iteration's ds_writes
  }

  // epilogue: O^T -> LDS transpose (reuse sK as sO[q][64+pad]) -> coalesced
  float inv0 = 1.0f / l_i[0], inv1 = 1.0f / l_i[1];
#pragma unroll
  for (int dt = 0; dt < 4; ++dt)
#pragma unroll
    for (int qtl = 0; qtl < 2; ++qtl) {
      float inv = qtl ? inv1 : inv0;
      floatx4 o = Oa[dt][qtl];
      half4 h;
      h[0] = (_Float16)(o[0] * inv); h[1] = (_Float16)(o[1] * inv);
      h[2] = (_Float16)(o[2] * inv); h[3] = (_Float16)(o[3] * inv);
      // q row = w*32+qtl*16+lr ; d = dt*16 + quad*4 + r
      *(half4*)&sK[(w * 32 + qtl * 16 + lr) * 72 + dt * 16 + quad * 4] = h;
    }
  __syncthreads();
#pragma unroll
  for (int it = 0; it < 2; ++it) {
    int row = (tid >> 2) + it * 64;
    int t = q0 + row;
    _Float16* orow = O + ((size_t)(bb * 2048 + t)) * 2048 + hh * 64;
#pragma unroll
    for (int cc = 0; cc < 2; ++cc) {
      int col = (tid & 3) * 16 + cc * 8;
      *(half8*)(orow + col) = *(const half8*)&sK[row * 72 + col];
    }
  }
}

// ---------------------------------------------------------------- launch
extern "C" void kernel_launch(void* const* d_in, const int* in_sizes, int n_in,
                              void* d_out, int out_size, void* d_ws, size_t ws_size,
                              hipStream_t stream) {
  (void)in_sizes; (void)n_in; (void)out_size; (void)ws_size;
  const float* x = (const float*)d_in[0];
  const float* Wqkv = (const float*)d_in[1];
  const float* bqkv = (const float*)d_in[2];
  const float* Wout = (const float*)d_in[3];
  const float* bout = (const float*)d_in[4];
  float* out = (float*)d_out;
  char* ws = (char*)d_ws;

  _Float16* xh    = (_Float16*)(ws + 0);
  _Float16* wqkvt = (_Float16*)(ws + 16777216);
  _Float16* Oh    = (_Float16*)(ws + 16777216);   // overlays wqkvt (dead)
  _Float16* Qh    = (_Float16*)(ws + 41943040);
  _Float16* Kh    = (_Float16*)(ws + 58720256);
  _Float16* Vth   = (_Float16*)(ws + 75497472);   // V^T, written by gemm<0>
  _Float16* woutt = (_Float16*)(ws + 92274688);   // total 96 MB

  cvt_x_kernel<<<4096, 256, 0, stream>>>(x, xh);
  cvt_wt_kernel<<<dim3(96, 32), 256, 0, stream>>>(Wqkv, wqkvt, 2048, 6144);
  cvt_wt_kernel<<<dim3(32, 32), 256, 0, stream>>>(Wout, woutt, 2048, 2048);
  gemm_f16_kernel<0><<<dim3(48, 32), 256, 0, stream>>>(
      xh, wqkvt, bqkv, 2048, 6144, Qh, Kh, Vth, nullptr);
  attn_kernel<<<dim3(64, 16), 256, 0, stream>>>(Qh, Kh, Vth, Oh);
  gemm_f16_kernel<1><<<dim3(16, 32), 256, 0, stream>>>(
      Oh, woutt, bout, 2048, 2048, nullptr, nullptr, nullptr, out);
}

// Round 7
// 402.336 us; speedup vs baseline: 1.4517x; 1.0760x over previous
//
#include <hip/hip_runtime.h>

// MHA fused pipeline for MI355X (gfx950), f16 MFMA + fp32 accumulate.
// Round 7:
//  - attn: paired q-tiles — block (bh, by) processes qt=15-by then qt=by,
//    so EVERY block runs exactly 17 kv-iterations. Grid 64x8=512 uniform
//    blocks (2/CU resident), no load-imbalance tail (round-4 counters showed
//    6.3% occupancy = starved CUs behind the 16-iter critical-path blocks).
//  - gemm<0>: sincosf -> __sincosf (hw v_sin/v_cos; libm range reduction was
//    ~40 VALU inst/call x 16/lane = the round-6 +7us regression).
//
// ws layout (bytes):
//   xh     @ 0          : 4096x2048 f16  (x cast)     [read by gemm<0>]
//   wqkvt  @ 16777216   : 6144x2048 f16  (Wqkv^T)    [dead after gemm<0>]
//   Oh     @ 16777216   : 4096x2048 f16  (attn out)   [overlays wqkvt]
//   Qh     @ 41943040   : [64 bh][2048][64] f16  (RoPE'd)
//   Kh     @ 58720256   : [64 bh][2048][64] f16  (RoPE'd)
//   Vth    @ 75497472   : [64 bh][64][2048] f16  (V^T, written by gemm<0>)
//   woutt  @ 92274688   : 2048x2048 f16  (Wout^T)
//   total 100663296 B = 96 MB

typedef _Float16 half8 __attribute__((ext_vector_type(8)));
typedef _Float16 half4 __attribute__((ext_vector_type(4)));
typedef float floatx4 __attribute__((ext_vector_type(4)));

#define GLD_LDS16(gp, sp)                                        \
  __builtin_amdgcn_global_load_lds(                              \
      (__attribute__((address_space(1))) void*)(gp),             \
      (__attribute__((address_space(3))) void*)(sp), 16, 0, 0)

__device__ __forceinline__ floatx4 mfma16(half8 a, half8 b, floatx4 c) {
  return __builtin_amdgcn_mfma_f32_16x16x32_f16(a, b, c, 0, 0, 0);
}
__device__ __forceinline__ floatx4 mfma16k16(half4 a, half4 b, floatx4 c) {
  return __builtin_amdgcn_mfma_f32_16x16x16f16(a, b, c, 0, 0, 0);
}

// ---------------------------------------------------------------- cvt_x
__global__ __launch_bounds__(256) void cvt_x_kernel(const float* __restrict__ x,
                                                    _Float16* __restrict__ xh) {
  int idx = blockIdx.x * 256 + threadIdx.x;  // 8 elems each, 8.4M total
  const floatx4* p = (const floatx4*)x + (size_t)idx * 2;
  floatx4 a = p[0], b = p[1];
  half8 o;
#pragma unroll
  for (int j = 0; j < 4; ++j) { o[j] = (_Float16)a[j]; o[4 + j] = (_Float16)b[j]; }
  *((half8*)xh + idx) = o;
}

// ------------------------------------------------------- cvt + transpose W
// W (Kd x Nd) f32 row-major  ->  Wt (Nd x Kd) f16 row-major
__global__ __launch_bounds__(256) void cvt_wt_kernel(const float* __restrict__ W,
                                                     _Float16* __restrict__ Wt,
                                                     int Kd, int Nd) {
  __shared__ float tile[64][65];
  int n0 = blockIdx.x * 64, k0 = blockIdx.y * 64;
  int tid = threadIdx.x;
#pragma unroll
  for (int it = 0; it < 4; ++it) {
    int r = (tid >> 4) + it * 16;   // k-local
    int c = (tid & 15) * 4;         // n-local
    floatx4 v = *(const floatx4*)(W + (size_t)(k0 + r) * Nd + n0 + c);
    tile[r][c + 0] = v[0]; tile[r][c + 1] = v[1];
    tile[r][c + 2] = v[2]; tile[r][c + 3] = v[3];
  }
  __syncthreads();
#pragma unroll
  for (int it = 0; it < 2; ++it) {
    int r = (tid >> 3) + it * 32;   // n-local
    int c = (tid & 7) * 8;          // k-local
    half8 o;
#pragma unroll
    for (int j = 0; j < 8; ++j) o[j] = (_Float16)tile[c + j][r];
    *(half8*)(Wt + (size_t)(n0 + r) * Kd + k0 + c) = o;
  }
}

// ---------------------------------------------------------------- GEMM
// C(128x128 tile) = A(MxK) @ Bt(NxK)^T + bias.
// MODE 0 epilogue: q/k blocks -> bias + in-register RoPE -> [bh][s][64];
//                  v blocks   -> bias + direct V^T [bh][d][s] half4 stores.
// MODE 1 epilogue: fp32 Co[m*Nd+n] + bias.
// Staging via global_load_lds width-16 + XOR swizzle (round-5, verified).
template <int MODE>
__global__ __launch_bounds__(256) void gemm_f16_kernel(
    const _Float16* __restrict__ A, const _Float16* __restrict__ Bt,
    const float* __restrict__ bias, int Kd, int Nd,
    _Float16* __restrict__ Qd, _Float16* __restrict__ Kkd,
    _Float16* __restrict__ Vd, float* __restrict__ Co) {
  __shared__ __align__(16) _Float16 sA[128 * 64];
  __shared__ __align__(16) _Float16 sB[128 * 64];
  int tid = threadIdx.x, w = tid >> 6, l = tid & 63;
  int lr = l & 15, lq = l >> 4;
  int m0 = blockIdx.y * 128, n0 = blockIdx.x * 128;
  int wrow = (w >> 1) * 64, wcol = (w & 1) * 64;

  floatx4 z4 = {0.f, 0.f, 0.f, 0.f};
  floatx4 acc[4][4];
#pragma unroll
  for (int i = 0; i < 4; ++i)
#pragma unroll
    for (int j = 0; j < 4; ++j) acc[i][j] = z4;

  // staging: wave w covers rows [w*32, w*32+32) (4 chunks x 8 rows)
  int srow = l >> 3;              // row within 8-row chunk
  int slot = (l & 7) ^ srow;      // XOR-swizzled global k8-chunk
  const _Float16* aG = A + (size_t)(m0 + w * 32 + srow) * Kd + slot * 8;
  const _Float16* bG = Bt + (size_t)(n0 + w * 32 + srow) * Kd + slot * 8;
  _Float16* sAw = &sA[w * 2048];
  _Float16* sBw = &sB[w * 2048];

  for (int kt = 0; kt < Kd; kt += 64) {
#pragma unroll
    for (int t = 0; t < 4; ++t) {
      GLD_LDS16(aG + (size_t)t * 8 * Kd + kt, sAw + t * 512);
      GLD_LDS16(bG + (size_t)t * 8 * Kd + kt, sBw + t * 512);
    }
    __syncthreads();
#pragma unroll
    for (int ks = 0; ks < 2; ++ks) {
      half8 af[4], bf[4];
#pragma unroll
      for (int i = 0; i < 4; ++i) {
        int ar = wrow + i * 16 + lr;
        int br = wcol + i * 16 + lr;
        int sl = (((ks << 2) | lq) ^ (lr & 7)) * 8;  // row&7 == lr&7
        af[i] = *(const half8*)&sA[ar * 64 + sl];
        bf[i] = *(const half8*)&sB[br * 64 + sl];
      }
#pragma unroll
      for (int i = 0; i < 4; ++i)
#pragma unroll
        for (int j = 0; j < 4; ++j) acc[i][j] = mfma16(af[i], bf[j], acc[i][j]);
    }
    __syncthreads();
  }

  // epilogue. C/D layout: col = lane&15, row = (lane>>4)*4 + reg (m89/m91).
  // Lane's 4 j-tiles hold d = lr, lr+16, lr+32, lr+48 within one head.
  if (MODE == 0) {
    int which = n0 >> 11;  // 0:q 1:k 2:v, uniform per block
    float bj[4];
#pragma unroll
    for (int j = 0; j < 4; ++j) bj[j] = bias[n0 + wcol + j * 16 + lr];
    int hh = ((n0 & 2047) + wcol) >> 6;
    if (which == 2) {
      // V^T: acc[i][j][r] -> Vd[bh][d=j*16+lr][t..t+3], half4 runs
#pragma unroll
      for (int j = 0; j < 4; ++j) {
        int dd = j * 16 + lr;
#pragma unroll
        for (int i = 0; i < 4; ++i) {
          int m = m0 + wrow + i * 16 + lq * 4;
          int bb = m >> 11, t = m & 2047;
          half4 h;
#pragma unroll
          for (int r = 0; r < 4; ++r) h[r] = (_Float16)(acc[i][j][r] + bj[j]);
          *(half4*)&Vd[(((size_t)(bb * 32 + hh)) * 64 + dd) * 2048 + t] = h;
        }
      }
    } else {
      _Float16* dst = which ? Kkd : Qd;
      // RoPE: pair (d=lr, d=lr+16) = (acc[i][0], acc[i][1]); freq per lane
      float freq = __expf(-(float)lr * 0.57564627324851148f);  // 10000^(-lr/16)
#pragma unroll
      for (int i = 0; i < 4; ++i)
#pragma unroll
        for (int r = 0; r < 4; ++r) {
          int m = m0 + wrow + i * 16 + lq * 4 + r;
          int bb = m >> 11, t = m & 2047;
          float sn, cs;
          __sincosf((float)t * freq, &sn, &cs);  // hw v_sin/v_cos path
          float x1 = acc[i][0][r] + bj[0];
          float x2 = acc[i][1][r] + bj[1];
          _Float16* row = dst + ((size_t)(bb * 32 + hh) * 2048 + (size_t)t) * 64;
          row[lr]      = (_Float16)(x1 * cs - x2 * sn);
          row[lr + 16] = (_Float16)(x1 * sn + x2 * cs);
          row[lr + 32] = (_Float16)(acc[i][2][r] + bj[2]);
          row[lr + 48] = (_Float16)(acc[i][3][r] + bj[3]);
        }
    }
  } else {
#pragma unroll
    for (int j = 0; j < 4; ++j) {
      int n = n0 + wcol + j * 16 + lr;
      float bj = bias[n];
#pragma unroll
      for (int i = 0; i < 4; ++i)
#pragma unroll
        for (int r = 0; r < 4; ++r) {
          int m = m0 + wrow + i * 16 + lq * 4 + r;
          Co[(size_t)m * Nd + n] = acc[i][j][r] + bj;
        }
    }
  }
}

// ---------------------------------------------------------------- attention
// Flash-style causal attention, S^T formulation + register prefetch +
// PAIRED q-tiles: block (bh, by) runs qt=15-by then qt=by -> every block
// does exactly 17 kv-iterations (uniform work, no imbalance tail).
__global__ __launch_bounds__(256) void attn_kernel(
    const _Float16* __restrict__ Q, const _Float16* __restrict__ Kk,
    const _Float16* __restrict__ Vt, _Float16* __restrict__ O) {
  constexpr int S = 2048;
  int bh = blockIdx.x;
  int by = blockIdx.y;  // 0..7
  int bb = bh >> 5, hh = bh & 31;
  const _Float16* Qb = Q + (size_t)bh * S * 64;
  const _Float16* Kb = Kk + (size_t)bh * S * 64;
  const _Float16* Vb = Vt + (size_t)bh * 64 * S;

  __shared__ __align__(16) _Float16 sK[128 * 72];   // [kv][64+pad], reused as sO
  __shared__ __align__(16) _Float16 sVt[64 * 136];  // [d][128+pad]

  int tid = threadIdx.x, w = tid >> 6, l = tid & 63;
  int lr = l & 15, quad = l >> 4;

  // staging lane geometry (shared by both halves)
  int rk = tid >> 3, ck = (tid & 7) * 8;   // K: 32 rows x 64d per pass
  int rv = tid >> 4, cv = (tid & 15) * 8;  // Vt: 16 rows x 128kv per pass
  const _Float16* Kst = Kb + (size_t)rk * 64 + ck;
  const _Float16* Vst = Vb + (size_t)rv * S + cv;

  int qts[2] = {15 - by, by};
  floatx4 z4 = {0.f, 0.f, 0.f, 0.f};

  for (int h = 0; h < 2; ++h) {
    int qt = qts[h];
    int q0 = qt * 128;

    // Q fragments as B-operand: B[k=d=quad*8+j][n=q=lane&15]; scale*log2e in.
    half8 qf[2][2];  // [qtile][ks]
#pragma unroll
    for (int qtl = 0; qtl < 2; ++qtl)
#pragma unroll
      for (int ks = 0; ks < 2; ++ks) {
        half8 v = *(const half8*)(Qb + (size_t)(q0 + w * 32 + qtl * 16 + lr) * 64 +
                                  ks * 32 + quad * 8);
        qf[qtl][ks] = v * (_Float16)0.18033688f;  // 0.125 * log2(e)
      }

    floatx4 Oa[4][2];  // [dt][qtile], C-layout row=d=quad*4+r, col=q=lane&15
    float m_i[2] = {-1e30f, -1e30f}, l_i[2] = {0.f, 0.f};
#pragma unroll
    for (int dt = 0; dt < 4; ++dt)
#pragma unroll
      for (int qtl = 0; qtl < 2; ++qtl) Oa[dt][qtl] = z4;

    // prefetch tile jt=0 of this half
    half8 kpre[4], vpre[4];
#pragma unroll
    for (int it = 0; it < 4; ++it) {
      kpre[it] = *(const half8*)(Kst + (size_t)it * 32 * 64);
      vpre[it] = *(const half8*)(Vst + (size_t)it * 16 * S);
    }

    for (int jt = 0; jt <= qt; ++jt) {
      // commit prefetched tile to LDS
#pragma unroll
      for (int it = 0; it < 4; ++it) {
        *(half8*)&sK[(rk + it * 32) * 72 + ck] = kpre[it];
        *(half8*)&sVt[(rv + it * 16) * 136 + cv] = vpre[it];
      }
      // issue next tile's loads; they fly during this iteration's compute
      if (jt < qt) {
        int kv1 = (jt + 1) * 128;
#pragma unroll
        for (int it = 0; it < 4; ++it) {
          kpre[it] = *(const half8*)(Kst + (size_t)(kv1 + it * 32) * 64);
          vpre[it] = *(const half8*)(Vst + kv1 + (size_t)it * 16 * S);
        }
      }
      __syncthreads();

      // S^T = K @ Q^T : rows kv (8 tiles), cols q (2 tiles per wave)
      floatx4 Sa[2][8];  // [qtile][kvt]
#pragma unroll
      for (int qtl = 0; qtl < 2; ++qtl)
#pragma unroll
        for (int kvt = 0; kvt < 8; ++kvt) Sa[qtl][kvt] = z4;
#pragma unroll
      for (int ks = 0; ks < 2; ++ks) {
#pragma unroll
        for (int kvt = 0; kvt < 8; ++kvt) {
          // A-frag: A[m=kv=lane&15][k=d=quad*8+j]
          half8 kf = *(const half8*)&sK[(kvt * 16 + lr) * 72 + ks * 32 + quad * 8];
          Sa[0][kvt] = mfma16(kf, qf[0][ks], Sa[0][kvt]);
          Sa[1][kvt] = mfma16(kf, qf[1][ks], Sa[1][kvt]);
        }
      }

      if (jt == qt) {  // causal mask on diagonal tile: kv_loc > q_loc
#pragma unroll
        for (int qtl = 0; qtl < 2; ++qtl) {
          int q_loc = w * 32 + qtl * 16 + lr;
#pragma unroll
          for (int kvt = 0; kvt < 8; ++kvt) {
            int kv_base = kvt * 16 + quad * 4;
#pragma unroll
            for (int r = 0; r < 4; ++r)
              if (kv_base + r > q_loc) Sa[qtl][kvt][r] = -1e30f;
          }
        }
      }

      // online softmax: per-lane column q, 32-reg reduce + 2 shuffles
#pragma unroll
      for (int qtl = 0; qtl < 2; ++qtl) {
        float mx = Sa[qtl][0][0];
#pragma unroll
        for (int kvt = 0; kvt < 8; ++kvt)
#pragma unroll
          for (int r = 0; r < 4; ++r) mx = fmaxf(mx, Sa[qtl][kvt][r]);
        mx = fmaxf(mx, __shfl_xor(mx, 16));
        mx = fmaxf(mx, __shfl_xor(mx, 32));
        float mnew = fmaxf(m_i[qtl], mx);
        float alpha = __builtin_amdgcn_exp2f(m_i[qtl] - mnew);
        m_i[qtl] = mnew;
        float rs = 0.f;
#pragma unroll
        for (int kvt = 0; kvt < 8; ++kvt)
#pragma unroll
          for (int r = 0; r < 4; ++r) {
            float p = __builtin_amdgcn_exp2f(Sa[qtl][kvt][r] - mnew);
            Sa[qtl][kvt][r] = p;
            rs += p;
          }
        rs += __shfl_xor(rs, 16);
        rs += __shfl_xor(rs, 32);
        l_i[qtl] = l_i[qtl] * alpha + rs;
#pragma unroll
        for (int dt = 0; dt < 4; ++dt) Oa[dt][qtl] *= alpha;
      }

      // O^T += V^T @ P^T, K=16 MFMA; P^T already in B-operand layout
#pragma unroll
      for (int kvt = 0; kvt < 8; ++kvt) {
        half4 vf[4];
#pragma unroll
        for (int dt = 0; dt < 4; ++dt)
          // A-frag: A[m=d=lane&15][k=kv=quad*4+j]
          vf[dt] = *(const half4*)&sVt[(dt * 16 + lr) * 136 + kvt * 16 + quad * 4];
        half4 pf[2];
#pragma unroll
        for (int qtl = 0; qtl < 2; ++qtl) {
          pf[qtl][0] = (_Float16)Sa[qtl][kvt][0];
          pf[qtl][1] = (_Float16)Sa[qtl][kvt][1];
          pf[qtl][2] = (_Float16)Sa[qtl][kvt][2];
          pf[qtl][3] = (_Float16)Sa[qtl][kvt][3];
        }
#pragma unroll
        for (int dt = 0; dt < 4; ++dt)
#pragma unroll
          for (int qtl = 0; qtl < 2; ++qtl)
            Oa[dt][qtl] = mfma16k16(vf[dt], pf[qtl], Oa[dt][qtl]);
      }
      __syncthreads();  // LDS reads done before next iteration's ds_writes
    }

    // epilogue: O^T -> LDS transpose (reuse sK as sO[q][64+pad]) -> coalesced
    float inv0 = 1.0f / l_i[0], inv1 = 1.0f / l_i[1];
#pragma unroll
    for (int dt = 0; dt < 4; ++dt)
#pragma unroll
      for (int qtl = 0; qtl < 2; ++qtl) {
        float inv = qtl ? inv1 : inv0;
        floatx4 o = Oa[dt][qtl];
        half4 hv;
        hv[0] = (_Float16)(o[0] * inv); hv[1] = (_Float16)(o[1] * inv);
        hv[2] = (_Float16)(o[2] * inv); hv[3] = (_Float16)(o[3] * inv);
        // q row = w*32+qtl*16+lr ; d = dt*16 + quad*4 + r
        *(half4*)&sK[(w * 32 + qtl * 16 + lr) * 72 + dt * 16 + quad * 4] = hv;
      }
    __syncthreads();
#pragma unroll
    for (int it = 0; it < 2; ++it) {
      int row = (tid >> 2) + it * 64;
      int t = q0 + row;
      _Float16* orow = O + ((size_t)(bb * 2048 + t)) * 2048 + hh * 64;
#pragma unroll
      for (int cc = 0; cc < 2; ++cc) {
        int col = (tid & 3) * 16 + cc * 8;
        *(half8*)(orow + col) = *(const half8*)&sK[row * 72 + col];
      }
    }
    __syncthreads();  // sK reads done before next half's staging writes
  }
}

// ---------------------------------------------------------------- launch
extern "C" void kernel_launch(void* const* d_in, const int* in_sizes, int n_in,
                              void* d_out, int out_size, void* d_ws, size_t ws_size,
                              hipStream_t stream) {
  (void)in_sizes; (void)n_in; (void)out_size; (void)ws_size;
  const float* x = (const float*)d_in[0];
  const float* Wqkv = (const float*)d_in[1];
  const float* bqkv = (const float*)d_in[2];
  const float* Wout = (const float*)d_in[3];
  const float* bout = (const float*)d_in[4];
  float* out = (float*)d_out;
  char* ws = (char*)d_ws;

  _Float16* xh    = (_Float16*)(ws + 0);
  _Float16* wqkvt = (_Float16*)(ws + 16777216);
  _Float16* Oh    = (_Float16*)(ws + 16777216);   // overlays wqkvt (dead)
  _Float16* Qh    = (_Float16*)(ws + 41943040);
  _Float16* Kh    = (_Float16*)(ws + 58720256);
  _Float16* Vth   = (_Float16*)(ws + 75497472);   // V^T, written by gemm<0>
  _Float16* woutt = (_Float16*)(ws + 92274688);   // total 96 MB

  cvt_x_kernel<<<4096, 256, 0, stream>>>(x, xh);
  cvt_wt_kernel<<<dim3(96, 32), 256, 0, stream>>>(Wqkv, wqkvt, 2048, 6144);
  cvt_wt_kernel<<<dim3(32, 32), 256, 0, stream>>>(Wout, woutt, 2048, 2048);
  gemm_f16_kernel<0><<<dim3(48, 32), 256, 0, stream>>>(
      xh, wqkvt, bqkv, 2048, 6144, Qh, Kh, Vth, nullptr);
  attn_kernel<<<dim3(64, 8), 256, 0, stream>>>(Qh, Kh, Vth, Oh);
  gemm_f16_kernel<1><<<dim3(16, 32), 256, 0, stream>>>(
      Oh, woutt, bout, 2048, 2048, nullptr, nullptr, nullptr, out);
}